// Round 3
// baseline (217.151 us; speedup 1.0000x reference)
//
#include <hip/hip_runtime.h>

#define C 128
#define G 8
#define KNN 16
#define QB 4
#define EPS 1e-5f

typedef unsigned short u16;
typedef __attribute__((ext_vector_type(8))) short short8;   // 8 bf16 = 4 VGPRs
typedef __attribute__((ext_vector_type(4))) float float4v;  // MFMA accumulator

union frag_u { short8 v; u16 u[8]; unsigned d[4]; };

__device__ inline u16 f2bf(float f) {
    unsigned u = __builtin_bit_cast(unsigned, f);
    unsigned r = (u + 0x7fffu + ((u >> 16) & 1u)) >> 16;
    return (u16)r;
}
__device__ inline float bf2f(u16 h) {
    unsigned u = ((unsigned)h) << 16;
    return __builtin_bit_cast(float, u);
}
// hardware packed f32->bf16 (RNE), 1 instr (guide T12 recipe, m240-verified)
__device__ inline unsigned pk2(float lo, float hi) {
    unsigned r;
    asm("v_cvt_pk_bf16_f32 %0, %1, %2" : "=v"(r) : "v"(lo), "v"(hi));
    return r;
}
__device__ inline u16 f2bf1(float f) { return (u16)pk2(f, f); }
__device__ inline float bflo(unsigned v) { return __builtin_bit_cast(float, v << 16); }
__device__ inline float bfhi(unsigned v) { return __builtin_bit_cast(float, v & 0xffff0000u); }

// ---------------------------------------------------------------------------
// Prep: swizzle weights into MFMA B-frag bf16 layout.  (byte-identical to the
// verified round-0 kernel)
// ---------------------------------------------------------------------------
__global__ __launch_bounds__(256) void prep_w(
    const float* __restrict__ Wk, const float* __restrict__ Wv,
    const float* __restrict__ Wq, const float* __restrict__ Wp2,
    const float* __restrict__ Ww1, const float* __restrict__ bp2,
    u16* __restrict__ dst, float* __restrict__ cw1)
{
    const int b = blockIdx.x, t = threadIdx.x;
    if (b < 16) {
        const int mi = b >> 2, qt = b & 3;
        const float* W = mi == 0 ? Wk : mi == 1 ? Wv : mi == 2 ? Wq : Wp2;
        u16* d = dst + mi * 16384;
        for (int e = qt * 4096 + t; e < (qt + 1) * 4096; e += 256) {
            const int k = e >> 7, n = e & 127;
            const int cb = n >> 4, lan = n & 15;
            const int kk = k >> 5, quad = (k >> 3) & 3, j = k & 7;
            d[(((cb * 4 + kk) * 4 + quad) * 16 + lan) * 8 + j] = f2bf(W[e]);
        }
    } else if (b == 16) {
        u16* d = dst + 4 * 16384;
        for (int e = t; e < 4096; e += 256) {
            const int j = e & 7, lan = (e >> 3) & 15;
            const int quad = (e >> 7) & 3, kk = e >> 9;
            const int k = kk * 32 + quad * 8 + j;
            d[e] = lan < 8 ? f2bf(Ww1[k * G + lan]) : (u16)0;
        }
    } else {
        // Wp2' = Wp2 @ Ww1 -> B-frag; cw1 = bp2 @ Ww1
        u16* d = dst + 4 * 16384 + 4096;
        for (int e = t; e < 4096; e += 256) d[e] = 0;
        __syncthreads();
#pragma unroll
        for (int it = 0; it < 4; it++) {
            const int k = it * 32 + (t >> 3), g = t & 7;
            float a = 0.f;
            for (int i = 0; i < C; i++)
                a = fmaf(Wp2[k * C + i], Ww1[i * G + g], a);
            const int kk = k >> 5, quad = (k >> 3) & 3, j = k & 7;
            d[((kk * 4 + quad) * 16 + g) * 8 + j] = f2bf(a);
        }
        if (t < G) {
            float a = 0.f;
            for (int i = 0; i < C; i++) a = fmaf(bp2[i], Ww1[i * G + t], a);
            cw1[t] = a;
        }
    }
}

// ---------------------------------------------------------------------------
// Fused projections.  (byte-identical to the verified round-0 kernel)
// ---------------------------------------------------------------------------
__global__ __launch_bounds__(256) void proj_all(
    const float* __restrict__ Xc, const float* __restrict__ Xq,
    const u16* __restrict__ PWk, const float* __restrict__ bk,
    const float* __restrict__ gk, const float* __restrict__ betak,
    const u16* __restrict__ PWv, const float* __restrict__ bv,
    const u16* __restrict__ PWq, const float* __restrict__ bq,
    const float* __restrict__ gq, const float* __restrict__ betaq,
    const u16* __restrict__ PWw1b,
    u16* __restrict__ vout, u16* __restrict__ Kp, u16* __restrict__ Qp,
    int nkv)
{
    __shared__ u16 Xs[64 * 136];
    const int t = threadIdx.x;
    const int w = t >> 6, l = t & 63;
    const int quad = l >> 4, lan = l & 15;
    const bool isq = (int)blockIdx.x >= nkv;
    const long long row0 = (long long)(isq ? blockIdx.x - nkv : blockIdx.x) * 64;
    const float* X = isq ? Xq : Xc;

    // stage X tile -> bf16 LDS
    {
        const float4* Xv = (const float4*)(X + row0 * C);
#pragma unroll
        for (int i = 0; i < 8; i++) {
            const int e = t + 256 * i;
            const int r = e >> 5, c4 = e & 31;
            const float4 f = Xv[e];
            uint2 p;
            p.x = (unsigned)f2bf(f.x) | ((unsigned)f2bf(f.y) << 16);
            p.y = (unsigned)f2bf(f.z) | ((unsigned)f2bf(f.w) << 16);
            *(uint2*)(&Xs[r * 136 + c4 * 4]) = p;
        }
    }
    __syncthreads();

    if (!isq) {
        // ---- v pass (bias only), packed bf16 in regs ----
        unsigned vp[2][4][2];
        {
            short8 Bf[2][4];
#pragma unroll
            for (int ct = 0; ct < 2; ct++) {
                const int cb = w * 2 + ct;
#pragma unroll
                for (int kk = 0; kk < 4; kk++)
                    Bf[ct][kk] = *(const short8*)(PWv + (((cb * 4 + kk) * 4 + quad) * 16 + lan) * 8);
            }
            float4v acc[2][4];
#pragma unroll
            for (int ct = 0; ct < 2; ct++)
#pragma unroll
                for (int rt = 0; rt < 4; rt++) acc[ct][rt] = (float4v)0.f;
#pragma unroll
            for (int rt = 0; rt < 4; rt++)
#pragma unroll
                for (int kk = 0; kk < 4; kk++) {
                    const short8 A = *(const short8*)(&Xs[(rt * 16 + lan) * 136 + kk * 32 + quad * 8]);
#pragma unroll
                    for (int ct = 0; ct < 2; ct++)
                        acc[ct][rt] = __builtin_amdgcn_mfma_f32_16x16x32_bf16(
                            A, Bf[ct][kk], acc[ct][rt], 0, 0, 0);
                }
#pragma unroll
            for (int ct = 0; ct < 2; ct++) {
                const float bb = bv[w * 32 + ct * 16 + lan];
#pragma unroll
                for (int rt = 0; rt < 4; rt++)
#pragma unroll
                    for (int h = 0; h < 2; h++)
                        vp[ct][rt][h] = (unsigned)f2bf(acc[ct][rt][2 * h] + bb)
                                      | ((unsigned)f2bf(acc[ct][rt][2 * h + 1] + bb) << 16);
            }
        }
        // ---- k pass (bn+relu), kept in regs ----
        float4v acck[2][4];
        {
            short8 Bf[2][4];
#pragma unroll
            for (int ct = 0; ct < 2; ct++) {
                const int cb = w * 2 + ct;
#pragma unroll
                for (int kk = 0; kk < 4; kk++)
                    Bf[ct][kk] = *(const short8*)(PWk + (((cb * 4 + kk) * 4 + quad) * 16 + lan) * 8);
            }
#pragma unroll
            for (int ct = 0; ct < 2; ct++)
#pragma unroll
                for (int rt = 0; rt < 4; rt++) acck[ct][rt] = (float4v)0.f;
#pragma unroll
            for (int rt = 0; rt < 4; rt++)
#pragma unroll
                for (int kk = 0; kk < 4; kk++) {
                    const short8 A = *(const short8*)(&Xs[(rt * 16 + lan) * 136 + kk * 32 + quad * 8]);
#pragma unroll
                    for (int ct = 0; ct < 2; ct++)
                        acck[ct][rt] = __builtin_amdgcn_mfma_f32_16x16x32_bf16(
                            A, Bf[ct][kk], acck[ct][rt], 0, 0, 0);
                }
        }
        __syncthreads();   // Xs A-reads done

        // k epilogue: bn+relu -> Xs (row-major bf16, A-frag-readable)
#pragma unroll
        for (int ct = 0; ct < 2; ct++) {
            const int cg = w * 32 + ct * 16 + lan;
            const float bb = bk[cg];
            const float sc = gk[cg] * rsqrtf(1.f + EPS);
            const float sh = betak[cg];
#pragma unroll
            for (int rt = 0; rt < 4; rt++)
#pragma unroll
                for (int reg = 0; reg < 4; reg++) {
                    float y = (acck[ct][rt][reg] + bb) * sc + sh;
                    y = y > 0.f ? y : 0.f;
                    Xs[(rt * 16 + quad * 4 + reg) * 136 + cg] = f2bf(y);
                }
        }
        __syncthreads();

        // K' = k @ Ww1 : wave w handles rows [16w,16w+16)
        {
            short8 Bw[4];
#pragma unroll
            for (int kk = 0; kk < 4; kk++)
                Bw[kk] = *(const short8*)(PWw1b + ((kk * 4 + quad) * 16 + lan) * 8);
            float4v ka = (float4v)0.f;
#pragma unroll
            for (int kk = 0; kk < 4; kk++) {
                const short8 A = *(const short8*)(&Xs[(w * 16 + lan) * 136 + kk * 32 + quad * 8]);
                ka = __builtin_amdgcn_mfma_f32_16x16x32_bf16(A, Bw[kk], ka, 0, 0, 0);
            }
            if (lan < G) {
#pragma unroll
                for (int reg = 0; reg < 4; reg++)
                    Kp[(row0 + w * 16 + quad * 4 + reg) * G + lan] = f2bf(ka[reg]);
            }
        }
        __syncthreads();   // Xs K'-reads done

        // v epilogue (unpack) -> Xs -> coalesced store
#pragma unroll
        for (int ct = 0; ct < 2; ct++) {
            const int cg = w * 32 + ct * 16 + lan;
#pragma unroll
            for (int rt = 0; rt < 4; rt++)
#pragma unroll
                for (int h = 0; h < 2; h++) {
                    Xs[(rt * 16 + quad * 4 + 2 * h) * 136 + cg]     = (u16)(vp[ct][rt][h] & 0xffffu);
                    Xs[(rt * 16 + quad * 4 + 2 * h + 1) * 136 + cg] = (u16)(vp[ct][rt][h] >> 16);
                }
        }
        __syncthreads();
#pragma unroll
        for (int i = 0; i < 4; i++) {
            const int e = t + 256 * i;
            const int r = e >> 4, cc = (e & 15) * 8;
            *(short8*)(vout + (row0 + r) * C + cc) = *(const short8*)(&Xs[r * 136 + cc]);
        }
    } else {
        // ---- q path: q = relu(bn(xq@Wq+bq)) in regs -> Xs -> Q' = q@Ww1 ----
        float4v acc[2][4];
        {
            short8 Bf[2][4];
#pragma unroll
            for (int ct = 0; ct < 2; ct++) {
                const int cb = w * 2 + ct;
#pragma unroll
                for (int kk = 0; kk < 4; kk++)
                    Bf[ct][kk] = *(const short8*)(PWq + (((cb * 4 + kk) * 4 + quad) * 16 + lan) * 8);
            }
#pragma unroll
            for (int ct = 0; ct < 2; ct++)
#pragma unroll
                for (int rt = 0; rt < 4; rt++) acc[ct][rt] = (float4v)0.f;
#pragma unroll
            for (int rt = 0; rt < 4; rt++)
#pragma unroll
                for (int kk = 0; kk < 4; kk++) {
                    const short8 A = *(const short8*)(&Xs[(rt * 16 + lan) * 136 + kk * 32 + quad * 8]);
#pragma unroll
                    for (int ct = 0; ct < 2; ct++)
                        acc[ct][rt] = __builtin_amdgcn_mfma_f32_16x16x32_bf16(
                            A, Bf[ct][kk], acc[ct][rt], 0, 0, 0);
                }
        }
        __syncthreads();
#pragma unroll
        for (int ct = 0; ct < 2; ct++) {
            const int cg = w * 32 + ct * 16 + lan;
            const float bb = bq[cg];
            const float sc = gq[cg] * rsqrtf(1.f + EPS);
            const float sh = betaq[cg];
#pragma unroll
            for (int rt = 0; rt < 4; rt++)
#pragma unroll
                for (int reg = 0; reg < 4; reg++) {
                    float y = (acc[ct][rt][reg] + bb) * sc + sh;
                    y = y > 0.f ? y : 0.f;
                    Xs[(rt * 16 + quad * 4 + reg) * 136 + cg] = f2bf(y);
                }
        }
        __syncthreads();
        {
            short8 Bw[4];
#pragma unroll
            for (int kk = 0; kk < 4; kk++)
                Bw[kk] = *(const short8*)(PWw1b + ((kk * 4 + quad) * 16 + lan) * 8);
            float4v qa = (float4v)0.f;
#pragma unroll
            for (int kk = 0; kk < 4; kk++) {
                const short8 A = *(const short8*)(&Xs[(w * 16 + lan) * 136 + kk * 32 + quad * 8]);
                qa = __builtin_amdgcn_mfma_f32_16x16x32_bf16(A, Bw[kk], qa, 0, 0, 0);
            }
            if (lan < G) {
#pragma unroll
                for (int reg = 0; reg < 4; reg++)
                    Qp[(row0 + w * 16 + quad * 4 + reg) * G + lan] = f2bf(qa[reg]);
            }
        }
    }
}

// ---------------------------------------------------------------------------
// Attention v6.5: round-0 structure exactly; ONLY local arithmetic identities:
//   P1: BN folded into Wp1 row-scale + hw cvt_pk store
//   P2: bp2 folded into MFMA accumulator init; P2b uses hw cvt_pk
//   P3: val packing via paired hw cvt_pk
// P0 / P5 (serial softmax) / P6 and all barriers identical to round 0.
// ---------------------------------------------------------------------------
__global__ __launch_bounds__(256) void attn6(
    const u16* __restrict__ vbuf, const u16* __restrict__ Kp,
    const u16* __restrict__ Qp,
    const float* __restrict__ qcoord, const float* __restrict__ ccoord,
    const float* __restrict__ Wp1, const float* __restrict__ bp1,
    const float* __restrict__ gp1, const float* __restrict__ betap1,
    const u16* __restrict__ PWp2, const float* __restrict__ bp2,
    const u16* __restrict__ PWp2pb, const float* __restrict__ cw1,
    const float* __restrict__ bw1,
    const float* __restrict__ gw1, const float* __restrict__ betaw1,
    const float* __restrict__ Ww2, const float* __restrict__ bw2,
    const int* __restrict__ knn, float* __restrict__ out)
{
    __shared__ u16   fA[64 * 136];    // h1 -> peb -> val
    __shared__ u16   kgs[64 * G];     // gathered K' rows (bf16)
    __shared__ float qps[QB * G];     // Q' rows (fp32)
    __shared__ float pebp[64 * G];    // PEB' (fp32)
    __shared__ float cw1s[G];
    __shared__ float pxs[64], pys[64], pzs[64];
    __shared__ int   idxs[64];
    __shared__ float wl[QB * 16 * G]; // hw -> weights (in place)

    const int t = threadIdx.x;
    const int w = t >> 6, l = t & 63;
    const int quad = l >> 4, lan = l & 15;
    const int m0 = blockIdx.x * QB;
    const int rsub = t >> 4;
    const int c8 = (t & 15) * 8;

    // ---- P0: v prefetch (regs), indices, positions, K'/Q'/cw1 to LDS ----
    float mfr[4];
    frag_u vg[4];
#pragma unroll
    for (int p = 0; p < 4; p++) {
        const int ii = knn[m0 * KNN + p * 16 + rsub];
        mfr[p] = ii >= 0 ? 1.f : 0.f;
        const size_t i0 = ii >= 0 ? ii : 0;
        vg[p].v = *(const short8*)(vbuf + i0 * C + c8);
    }
    if (t < 64) {
        const int q = t >> 4;
        const int ii = knn[m0 * KNN + t];
        const float mf = ii >= 0 ? 1.f : 0.f;
        const int i0 = ii >= 0 ? ii : 0;
        idxs[t] = ii;
        pxs[t] = (ccoord[i0 * 3 + 0] - qcoord[(m0 + q) * 3 + 0]) * mf;
        pys[t] = (ccoord[i0 * 3 + 1] - qcoord[(m0 + q) * 3 + 1]) * mf;
        pzs[t] = (ccoord[i0 * 3 + 2] - qcoord[(m0 + q) * 3 + 2]) * mf;
        *(short8*)(&kgs[t * G]) = *(const short8*)(Kp + (size_t)i0 * G);
    } else if (t < 68) {
        const int p = t - 64;
        frag_u qv;
        qv.v = *(const short8*)(Qp + (size_t)(m0 + p) * G);
#pragma unroll
        for (int j = 0; j < G; j++) qps[p * G + j] = bf2f(qv.u[j]);
    } else if (t < 76) {
        cw1s[t - 68] = cw1[t - 68];
    }
    __syncthreads();

    // ---- P1: h1 = relu(bn(pos @ Wp1 + bp1)) -> fA bf16 (A-frag layout) ----
    // BN folded: w0..w2 pre-scaled by sc, shift folded into bias.
    {
        const int c = t & 127, hh = t >> 7;
        const float sc = gp1[c] * rsqrtf(1.f + EPS);
        const float w0 = Wp1[c] * sc, w1_ = Wp1[C + c] * sc, w2_ = Wp1[2 * C + c] * sc;
        const float bb = fmaf(bp1[c], sc, betap1[c]);
#pragma unroll
        for (int r2 = 0; r2 < 32; r2++) {
            const int r = hh * 32 + r2;
            float y = fmaf(pxs[r], w0, fmaf(pys[r], w1_, fmaf(pzs[r], w2_, bb)));
            y = y > 0.f ? y : 0.f;
            fA[r * 136 + c] = f2bf1(y);
        }
    }
    __syncthreads();

    // ---- P2: peb = h1 @ Wp2 (+bp2 via acc init) + PEB' = h1 @ Wp2' ----
    float4v acc[2][4];
    float4v pp = (float4v)0.f;
    {
        short8 Bf[2][4];
#pragma unroll
        for (int ct = 0; ct < 2; ct++) {
            const int cb = w * 2 + ct;
#pragma unroll
            for (int kk = 0; kk < 4; kk++)
                Bf[ct][kk] = *(const short8*)(PWp2 + (((cb * 4 + kk) * 4 + quad) * 16 + lan) * 8);
        }
        const float b0 = bp2[w * 32 + lan], b1 = bp2[w * 32 + 16 + lan];
#pragma unroll
        for (int q = 0; q < 4; q++) {
            acc[0][q] = (float4v)b0;
            acc[1][q] = (float4v)b1;
        }
#pragma unroll
        for (int q = 0; q < 4; q++)
#pragma unroll
            for (int kk = 0; kk < 4; kk++) {
                const short8 A = *(const short8*)(&fA[(q * 16 + lan) * 136 + kk * 32 + quad * 8]);
#pragma unroll
                for (int ct = 0; ct < 2; ct++)
                    acc[ct][q] = __builtin_amdgcn_mfma_f32_16x16x32_bf16(
                        A, Bf[ct][kk], acc[ct][q], 0, 0, 0);
            }
        // PEB': wave w -> rows [16w,16w+16)
#pragma unroll
        for (int kk = 0; kk < 4; kk++) {
            const short8 Bp = *(const short8*)(PWp2pb + ((kk * 4 + quad) * 16 + lan) * 8);
            const short8 A = *(const short8*)(&fA[(w * 16 + lan) * 136 + kk * 32 + quad * 8]);
            pp = __builtin_amdgcn_mfma_f32_16x16x32_bf16(A, Bp, pp, 0, 0, 0);
        }
    }
    __syncthreads();   // all h1 reads done

    // ---- P2b: scatter peb (bf16, in place) and PEB' (fp32) ----
    {
#pragma unroll
        for (int ct = 0; ct < 2; ct++)
#pragma unroll
            for (int q = 0; q < 4; q++)
#pragma unroll
                for (int reg = 0; reg < 4; reg++)
                    fA[(q * 16 + quad * 4 + reg) * 136 + w * 32 + ct * 16 + lan] =
                        f2bf1(acc[ct][q][reg]);
        if (lan < G) {
#pragma unroll
            for (int reg = 0; reg < 4; reg++)
                pebp[(w * 16 + quad * 4 + reg) * G + lan] = pp[reg];
        }
    }
    __syncthreads();

    // ---- P3: val = vg*mf + peb -> fA (in place); logits -> wl ----
    {
#pragma unroll
        for (int p = 0; p < 4; p++) {
            const int r = p * 16 + rsub;
            const float mf = mfr[p];
            frag_u peb, o;
            peb.v = *(const short8*)(&fA[r * 136 + c8]);
#pragma unroll
            for (int dd = 0; dd < 4; dd++) {
                const unsigned pv = peb.d[dd], vv = vg[p].d[dd];
                o.d[dd] = pk2(fmaf(bflo(vv), mf, bflo(pv)),
                              fmaf(bfhi(vv), mf, bfhi(pv)));
            }
            *(short8*)(&fA[r * 136 + c8]) = o.v;   // exclusive slot
        }
    }
    if (t < 64) {
        const int q = t >> 4, j = t & 15;
        const float mf = idxs[t] >= 0 ? 1.f : 0.f;
#pragma unroll
        for (int g = 0; g < G; g++) {
            const float L = bf2f(kgs[t * G + g]) * mf - qps[q * G + g]
                          + pebp[t * G + g] + cw1s[g] + bw1[g];
            const float y = L * (gw1[g] * rsqrtf(1.f + EPS)) + betaw1[g];
            wl[q * 128 + j * G + g] = y > 0.f ? y : 0.f;
        }
    }
    __syncthreads();

    // ---- P5: logits = hw @ Ww2 + bw2; softmax; * mask (wl in place) ----
    if (t < QB * G) {
        const int q = t >> 3, g2 = t & 7;
        float w2c[G];
#pragma unroll
        for (int g = 0; g < G; g++) w2c[g] = Ww2[g * G + g2];
        const float bb = bw2[g2];
        float lg[KNN], mx = -1e30f;
#pragma unroll
        for (int j = 0; j < KNN; j++) {
            float a = bb;
#pragma unroll
            for (int g = 0; g < G; g++) a = fmaf(wl[q * 128 + j * 8 + g], w2c[g], a);
            lg[j] = a;
            mx = fmaxf(mx, a);
        }
        float sum = 0.f;
#pragma unroll
        for (int j = 0; j < KNN; j++) { lg[j] = __expf(lg[j] - mx); sum += lg[j]; }
        const float inv = 1.f / sum;
#pragma unroll
        for (int j = 0; j < KNN; j++) {
            const float mf = idxs[q * 16 + j] >= 0 ? 1.f : 0.f;
            wl[q * 128 + j * 8 + g2] = lg[j] * inv * mf;
        }
    }
    __syncthreads();

    // ---- P6: out[q][c] = sum_j val[j][c] * w[j][c>>4] ----
#pragma unroll
    for (int i = 0; i < 2; i++) {
        const int e = t + 256 * i;
        const int q = e >> 7, c = e & 127, g = c >> 4;
        float a = 0.f;
#pragma unroll
        for (int j = 0; j < KNN; j++)
            a = fmaf(bf2f(fA[(q * 16 + j) * 136 + c]), wl[q * 128 + j * 8 + g], a);
        out[(size_t)(m0 + q) * C + c] = a;
    }
}

// ---------------------------------------------------------------------------
extern "C" void kernel_launch(void* const* d_in, const int* in_sizes, int n_in,
                              void* d_out, int out_size, void* d_ws, size_t ws_size,
                              hipStream_t stream)
{
    const float* query_feat    = (const float*)d_in[0];
    const float* context_feat  = (const float*)d_in[1];
    const float* query_coord   = (const float*)d_in[2];
    const float* context_coord = (const float*)d_in[3];
    const float* Wq    = (const float*)d_in[4];
    const float* bq    = (const float*)d_in[5];
    const float* gq    = (const float*)d_in[6];
    const float* betaq = (const float*)d_in[7];
    const float* Wk    = (const float*)d_in[8];
    const float* bk    = (const float*)d_in[9];
    const float* gk    = (const float*)d_in[10];
    const float* betak = (const float*)d_in[11];
    const float* Wv    = (const float*)d_in[12];
    const float* bv    = (const float*)d_in[13];
    const float* Wp1   = (const float*)d_in[14];
    const float* bp1   = (const float*)d_in[15];
    const float* gp1   = (const float*)d_in[16];
    const float* betap1= (const float*)d_in[17];
    const float* Wp2   = (const float*)d_in[18];
    const float* bp2   = (const float*)d_in[19];
    const float* Ww1   = (const float*)d_in[20];
    const float* bw1   = (const float*)d_in[21];
    const float* gw1   = (const float*)d_in[22];
    const float* betaw1= (const float*)d_in[23];
    const float* Ww2   = (const float*)d_in[24];
    const float* bw2   = (const float*)d_in[25];
    const int*   knn   = (const int*)d_in[26];

    const int M = in_sizes[0] / C;   // 16384
    const int N = in_sizes[1] / C;   // 131072

    // workspace: v (N*C bf16) | K' (N*G bf16) | Q' (M*G bf16) | prepped weights | cw1
    u16* vb = (u16*)d_ws;
    u16* Kp = vb + (size_t)N * C;
    u16* Qp = Kp + (size_t)N * G;
    u16* pw = Qp + (size_t)M * G;
    u16* pWk    = pw;
    u16* pWv    = pw + 16384;
    u16* pWq    = pw + 2 * 16384;
    u16* pWp2   = pw + 3 * 16384;
    u16* pWw1b  = pw + 4 * 16384;
    u16* pWp2pb = pw + 4 * 16384 + 4096;
    float* cw1  = (float*)(pw + 4 * 16384 + 2 * 4096);

    prep_w<<<18, 256, 0, stream>>>(Wk, Wv, Wq, Wp2, Ww1, bp2, pw, cw1);
    proj_all<<<N / 64 + M / 64, 256, 0, stream>>>(
        context_feat, query_feat,
        pWk, bk, gk, betak, pWv, bv,
        pWq, bq, gq, betaq, pWw1b,
        vb, Kp, Qp, N / 64);
    attn6<<<M / QB, 256, 0, stream>>>(vb, Kp, Qp, query_coord, context_coord,
                                      Wp1, bp1, gp1, betap1, pWp2, bp2,
                                      pWp2pb, cw1, bw1, gw1, betaw1, Ww2, bw2,
                                      knn, (float*)d_out);
}

// Round 4
// 214.406 us; speedup vs baseline: 1.0128x; 1.0128x over previous
//
#include <hip/hip_runtime.h>

#define C 128
#define G 8
#define KNN 16
#define QB 4
#define EPS 1e-5f

typedef unsigned short u16;
typedef __attribute__((ext_vector_type(8))) short short8;   // 8 bf16 = 4 VGPRs
typedef __attribute__((ext_vector_type(4))) float float4v;  // MFMA accumulator

union frag_u { short8 v; u16 u[8]; unsigned d[4]; };

__device__ inline u16 f2bf(float f) {
    unsigned u = __builtin_bit_cast(unsigned, f);
    unsigned r = (u + 0x7fffu + ((u >> 16) & 1u)) >> 16;
    return (u16)r;
}
__device__ inline float bf2f(u16 h) {
    unsigned u = ((unsigned)h) << 16;
    return __builtin_bit_cast(float, u);
}
// hardware packed f32->bf16 (RNE), 1 instr (guide T12 recipe, verified r3)
__device__ inline unsigned pk2(float lo, float hi) {
    unsigned r;
    asm("v_cvt_pk_bf16_f32 %0, %1, %2" : "=v"(r) : "v"(lo), "v"(hi));
    return r;
}
__device__ inline u16 f2bf1(float f) { return (u16)pk2(f, f); }
__device__ inline float bflo(unsigned v) { return __builtin_bit_cast(float, v << 16); }
__device__ inline float bfhi(unsigned v) { return __builtin_bit_cast(float, v & 0xffff0000u); }

// ---------------------------------------------------------------------------
// Prep: swizzle weights into MFMA B-frag bf16 layout.
// Block 17 (Wp2@Ww1) rewritten: Ww1 staged in LDS, Wp2 read as float4,
// unrolled -> kills the 512-deep serial global-load fma chain.
// ---------------------------------------------------------------------------
__global__ __launch_bounds__(256) void prep_w(
    const float* __restrict__ Wk, const float* __restrict__ Wv,
    const float* __restrict__ Wq, const float* __restrict__ Wp2,
    const float* __restrict__ Ww1, const float* __restrict__ bp2,
    u16* __restrict__ dst, float* __restrict__ cw1)
{
    __shared__ float w1s[C * G];
    const int b = blockIdx.x, t = threadIdx.x;
    if (b < 16) {
        const int mi = b >> 2, qt = b & 3;
        const float* W = mi == 0 ? Wk : mi == 1 ? Wv : mi == 2 ? Wq : Wp2;
        u16* d = dst + mi * 16384;
        for (int e = qt * 4096 + t; e < (qt + 1) * 4096; e += 256) {
            const int k = e >> 7, n = e & 127;
            const int cb = n >> 4, lan = n & 15;
            const int kk = k >> 5, quad = (k >> 3) & 3, j = k & 7;
            d[(((cb * 4 + kk) * 4 + quad) * 16 + lan) * 8 + j] = f2bf(W[e]);
        }
    } else if (b == 16) {
        u16* d = dst + 4 * 16384;
        for (int e = t; e < 4096; e += 256) {
            const int j = e & 7, lan = (e >> 3) & 15;
            const int quad = (e >> 7) & 3, kk = e >> 9;
            const int k = kk * 32 + quad * 8 + j;
            d[e] = lan < 8 ? f2bf(Ww1[k * G + lan]) : (u16)0;
        }
    } else {
        // Wp2' = Wp2 @ Ww1 -> B-frag; cw1 = bp2 @ Ww1   (Ww1 from LDS)
        u16* d = dst + 4 * 16384 + 4096;
        for (int e = t; e < 4096; e += 256) d[e] = 0;
        for (int e = t; e < C * G; e += 256) w1s[e] = Ww1[e];
        __syncthreads();
#pragma unroll
        for (int it = 0; it < 4; it++) {
            const int k = it * 32 + (t >> 3), g = t & 7;
            const float4* Wr = (const float4*)(Wp2 + k * C);
            float a = 0.f;
#pragma unroll 8
            for (int i4 = 0; i4 < 32; i4++) {
                const float4 wv = Wr[i4];
                a = fmaf(wv.x, w1s[(i4 * 4 + 0) * G + g], a);
                a = fmaf(wv.y, w1s[(i4 * 4 + 1) * G + g], a);
                a = fmaf(wv.z, w1s[(i4 * 4 + 2) * G + g], a);
                a = fmaf(wv.w, w1s[(i4 * 4 + 3) * G + g], a);
            }
            const int kk = k >> 5, quad = (k >> 3) & 3, j = k & 7;
            d[((kk * 4 + quad) * 16 + g) * 8 + j] = f2bf(a);
        }
        if (t < G) {
            float a = 0.f;
#pragma unroll 8
            for (int i = 0; i < C; i++) a = fmaf(bp2[i], w1s[i * G + t], a);
            cw1[t] = a;
        }
    }
}

// ---------------------------------------------------------------------------
// Fused projections.  (byte-identical to the verified round-3 kernel)
// ---------------------------------------------------------------------------
__global__ __launch_bounds__(256) void proj_all(
    const float* __restrict__ Xc, const float* __restrict__ Xq,
    const u16* __restrict__ PWk, const float* __restrict__ bk,
    const float* __restrict__ gk, const float* __restrict__ betak,
    const u16* __restrict__ PWv, const float* __restrict__ bv,
    const u16* __restrict__ PWq, const float* __restrict__ bq,
    const float* __restrict__ gq, const float* __restrict__ betaq,
    const u16* __restrict__ PWw1b,
    u16* __restrict__ vout, u16* __restrict__ Kp, u16* __restrict__ Qp,
    int nkv)
{
    __shared__ u16 Xs[64 * 136];
    const int t = threadIdx.x;
    const int w = t >> 6, l = t & 63;
    const int quad = l >> 4, lan = l & 15;
    const bool isq = (int)blockIdx.x >= nkv;
    const long long row0 = (long long)(isq ? blockIdx.x - nkv : blockIdx.x) * 64;
    const float* X = isq ? Xq : Xc;

    // stage X tile -> bf16 LDS
    {
        const float4* Xv = (const float4*)(X + row0 * C);
#pragma unroll
        for (int i = 0; i < 8; i++) {
            const int e = t + 256 * i;
            const int r = e >> 5, c4 = e & 31;
            const float4 f = Xv[e];
            uint2 p;
            p.x = (unsigned)f2bf(f.x) | ((unsigned)f2bf(f.y) << 16);
            p.y = (unsigned)f2bf(f.z) | ((unsigned)f2bf(f.w) << 16);
            *(uint2*)(&Xs[r * 136 + c4 * 4]) = p;
        }
    }
    __syncthreads();

    if (!isq) {
        // ---- v pass (bias only), packed bf16 in regs ----
        unsigned vp[2][4][2];
        {
            short8 Bf[2][4];
#pragma unroll
            for (int ct = 0; ct < 2; ct++) {
                const int cb = w * 2 + ct;
#pragma unroll
                for (int kk = 0; kk < 4; kk++)
                    Bf[ct][kk] = *(const short8*)(PWv + (((cb * 4 + kk) * 4 + quad) * 16 + lan) * 8);
            }
            float4v acc[2][4];
#pragma unroll
            for (int ct = 0; ct < 2; ct++)
#pragma unroll
                for (int rt = 0; rt < 4; rt++) acc[ct][rt] = (float4v)0.f;
#pragma unroll
            for (int rt = 0; rt < 4; rt++)
#pragma unroll
                for (int kk = 0; kk < 4; kk++) {
                    const short8 A = *(const short8*)(&Xs[(rt * 16 + lan) * 136 + kk * 32 + quad * 8]);
#pragma unroll
                    for (int ct = 0; ct < 2; ct++)
                        acc[ct][rt] = __builtin_amdgcn_mfma_f32_16x16x32_bf16(
                            A, Bf[ct][kk], acc[ct][rt], 0, 0, 0);
                }
#pragma unroll
            for (int ct = 0; ct < 2; ct++) {
                const float bb = bv[w * 32 + ct * 16 + lan];
#pragma unroll
                for (int rt = 0; rt < 4; rt++)
#pragma unroll
                    for (int h = 0; h < 2; h++)
                        vp[ct][rt][h] = (unsigned)f2bf(acc[ct][rt][2 * h] + bb)
                                      | ((unsigned)f2bf(acc[ct][rt][2 * h + 1] + bb) << 16);
            }
        }
        // ---- k pass (bn+relu), kept in regs ----
        float4v acck[2][4];
        {
            short8 Bf[2][4];
#pragma unroll
            for (int ct = 0; ct < 2; ct++) {
                const int cb = w * 2 + ct;
#pragma unroll
                for (int kk = 0; kk < 4; kk++)
                    Bf[ct][kk] = *(const short8*)(PWk + (((cb * 4 + kk) * 4 + quad) * 16 + lan) * 8);
            }
#pragma unroll
            for (int ct = 0; ct < 2; ct++)
#pragma unroll
                for (int rt = 0; rt < 4; rt++) acck[ct][rt] = (float4v)0.f;
#pragma unroll
            for (int rt = 0; rt < 4; rt++)
#pragma unroll
                for (int kk = 0; kk < 4; kk++) {
                    const short8 A = *(const short8*)(&Xs[(rt * 16 + lan) * 136 + kk * 32 + quad * 8]);
#pragma unroll
                    for (int ct = 0; ct < 2; ct++)
                        acck[ct][rt] = __builtin_amdgcn_mfma_f32_16x16x32_bf16(
                            A, Bf[ct][kk], acck[ct][rt], 0, 0, 0);
                }
        }
        __syncthreads();   // Xs A-reads done

        // k epilogue: bn+relu -> Xs (row-major bf16, A-frag-readable)
#pragma unroll
        for (int ct = 0; ct < 2; ct++) {
            const int cg = w * 32 + ct * 16 + lan;
            const float bb = bk[cg];
            const float sc = gk[cg] * rsqrtf(1.f + EPS);
            const float sh = betak[cg];
#pragma unroll
            for (int rt = 0; rt < 4; rt++)
#pragma unroll
                for (int reg = 0; reg < 4; reg++) {
                    float y = (acck[ct][rt][reg] + bb) * sc + sh;
                    y = y > 0.f ? y : 0.f;
                    Xs[(rt * 16 + quad * 4 + reg) * 136 + cg] = f2bf(y);
                }
        }
        __syncthreads();

        // K' = k @ Ww1 : wave w handles rows [16w,16w+16)
        {
            short8 Bw[4];
#pragma unroll
            for (int kk = 0; kk < 4; kk++)
                Bw[kk] = *(const short8*)(PWw1b + ((kk * 4 + quad) * 16 + lan) * 8);
            float4v ka = (float4v)0.f;
#pragma unroll
            for (int kk = 0; kk < 4; kk++) {
                const short8 A = *(const short8*)(&Xs[(w * 16 + lan) * 136 + kk * 32 + quad * 8]);
                ka = __builtin_amdgcn_mfma_f32_16x16x32_bf16(A, Bw[kk], ka, 0, 0, 0);
            }
            if (lan < G) {
#pragma unroll
                for (int reg = 0; reg < 4; reg++)
                    Kp[(row0 + w * 16 + quad * 4 + reg) * G + lan] = f2bf(ka[reg]);
            }
        }
        __syncthreads();   // Xs K'-reads done

        // v epilogue (unpack) -> Xs -> coalesced store
#pragma unroll
        for (int ct = 0; ct < 2; ct++) {
            const int cg = w * 32 + ct * 16 + lan;
#pragma unroll
            for (int rt = 0; rt < 4; rt++)
#pragma unroll
                for (int h = 0; h < 2; h++) {
                    Xs[(rt * 16 + quad * 4 + 2 * h) * 136 + cg]     = (u16)(vp[ct][rt][h] & 0xffffu);
                    Xs[(rt * 16 + quad * 4 + 2 * h + 1) * 136 + cg] = (u16)(vp[ct][rt][h] >> 16);
                }
        }
        __syncthreads();
#pragma unroll
        for (int i = 0; i < 4; i++) {
            const int e = t + 256 * i;
            const int r = e >> 4, cc = (e & 15) * 8;
            *(short8*)(vout + (row0 + r) * C + cc) = *(const short8*)(&Xs[r * 136 + cc]);
        }
    } else {
        // ---- q path: q = relu(bn(xq@Wq+bq)) in regs -> Xs -> Q' = q@Ww1 ----
        float4v acc[2][4];
        {
            short8 Bf[2][4];
#pragma unroll
            for (int ct = 0; ct < 2; ct++) {
                const int cb = w * 2 + ct;
#pragma unroll
                for (int kk = 0; kk < 4; kk++)
                    Bf[ct][kk] = *(const short8*)(PWq + (((cb * 4 + kk) * 4 + quad) * 16 + lan) * 8);
            }
#pragma unroll
            for (int ct = 0; ct < 2; ct++)
#pragma unroll
                for (int rt = 0; rt < 4; rt++) acc[ct][rt] = (float4v)0.f;
#pragma unroll
            for (int rt = 0; rt < 4; rt++)
#pragma unroll
                for (int kk = 0; kk < 4; kk++) {
                    const short8 A = *(const short8*)(&Xs[(rt * 16 + lan) * 136 + kk * 32 + quad * 8]);
#pragma unroll
                    for (int ct = 0; ct < 2; ct++)
                        acc[ct][rt] = __builtin_amdgcn_mfma_f32_16x16x32_bf16(
                            A, Bf[ct][kk], acc[ct][rt], 0, 0, 0);
                }
        }
        __syncthreads();
#pragma unroll
        for (int ct = 0; ct < 2; ct++) {
            const int cg = w * 32 + ct * 16 + lan;
            const float bb = bq[cg];
            const float sc = gq[cg] * rsqrtf(1.f + EPS);
            const float sh = betaq[cg];
#pragma unroll
            for (int rt = 0; rt < 4; rt++)
#pragma unroll
                for (int reg = 0; reg < 4; reg++) {
                    float y = (acc[ct][rt][reg] + bb) * sc + sh;
                    y = y > 0.f ? y : 0.f;
                    Xs[(rt * 16 + quad * 4 + reg) * 136 + cg] = f2bf(y);
                }
        }
        __syncthreads();
        {
            short8 Bw[4];
#pragma unroll
            for (int kk = 0; kk < 4; kk++)
                Bw[kk] = *(const short8*)(PWw1b + ((kk * 4 + quad) * 16 + lan) * 8);
            float4v qa = (float4v)0.f;
#pragma unroll
            for (int kk = 0; kk < 4; kk++) {
                const short8 A = *(const short8*)(&Xs[(w * 16 + lan) * 136 + kk * 32 + quad * 8]);
                qa = __builtin_amdgcn_mfma_f32_16x16x32_bf16(A, Bw[kk], qa, 0, 0, 0);
            }
            if (lan < G) {
#pragma unroll
                for (int reg = 0; reg < 4; reg++)
                    Qp[(row0 + w * 16 + quad * 4 + reg) * G + lan] = f2bf(qa[reg]);
            }
        }
    }
}

// ---------------------------------------------------------------------------
// Attention v6.6 = verified v6.5 + wave-parallel logits/softmax:
//   lane (wave w = query, j = lane&15 = neighbor, quad = lane>>4 = group pair)
//   logits all-lane -> wl; butterfly shfl_xor max/sum over 16-lane groups.
// Same arithmetic as the serial P5 (same fma order for Ww2 dot); barrier
// count unchanged (logits merged into P3's slot).
// ---------------------------------------------------------------------------
__global__ __launch_bounds__(256) void attn6(
    const u16* __restrict__ vbuf, const u16* __restrict__ Kp,
    const u16* __restrict__ Qp,
    const float* __restrict__ qcoord, const float* __restrict__ ccoord,
    const float* __restrict__ Wp1, const float* __restrict__ bp1,
    const float* __restrict__ gp1, const float* __restrict__ betap1,
    const u16* __restrict__ PWp2, const float* __restrict__ bp2,
    const u16* __restrict__ PWp2pb, const float* __restrict__ cw1,
    const float* __restrict__ bw1,
    const float* __restrict__ gw1, const float* __restrict__ betaw1,
    const float* __restrict__ Ww2, const float* __restrict__ bw2,
    const int* __restrict__ knn, float* __restrict__ out)
{
    __shared__ u16   fA[64 * 136];    // h1 -> peb -> val
    __shared__ u16   kgs[64 * G];     // gathered K' rows (bf16)
    __shared__ float qps[QB * G];     // Q' rows (fp32)
    __shared__ float pebp[64 * G];    // PEB' (fp32)
    __shared__ float cw1s[G];
    __shared__ float ww2s[G * G];     // Ww2 staged once
    __shared__ float pxs[64], pys[64], pzs[64];
    __shared__ int   idxs[64];
    __shared__ float wl[QB * 16 * G]; // hw -> weights (in place)

    const int t = threadIdx.x;
    const int w = t >> 6, l = t & 63;
    const int quad = l >> 4, lan = l & 15;
    const int m0 = blockIdx.x * QB;
    const int rsub = t >> 4;
    const int c8 = (t & 15) * 8;

    // ---- P0: v prefetch (regs), indices, positions, K'/Q'/cw1/Ww2 to LDS ----
    float mfr[4];
    frag_u vg[4];
#pragma unroll
    for (int p = 0; p < 4; p++) {
        const int ii = knn[m0 * KNN + p * 16 + rsub];
        mfr[p] = ii >= 0 ? 1.f : 0.f;
        const size_t i0 = ii >= 0 ? ii : 0;
        vg[p].v = *(const short8*)(vbuf + i0 * C + c8);
    }
    if (t < 64) {
        const int q = t >> 4;
        const int ii = knn[m0 * KNN + t];
        const float mf = ii >= 0 ? 1.f : 0.f;
        const int i0 = ii >= 0 ? ii : 0;
        idxs[t] = ii;
        pxs[t] = (ccoord[i0 * 3 + 0] - qcoord[(m0 + q) * 3 + 0]) * mf;
        pys[t] = (ccoord[i0 * 3 + 1] - qcoord[(m0 + q) * 3 + 1]) * mf;
        pzs[t] = (ccoord[i0 * 3 + 2] - qcoord[(m0 + q) * 3 + 2]) * mf;
        *(short8*)(&kgs[t * G]) = *(const short8*)(Kp + (size_t)i0 * G);
    } else if (t < 68) {
        const int p = t - 64;
        frag_u qv;
        qv.v = *(const short8*)(Qp + (size_t)(m0 + p) * G);
#pragma unroll
        for (int j = 0; j < G; j++) qps[p * G + j] = bf2f(qv.u[j]);
    } else if (t < 76) {
        cw1s[t - 68] = cw1[t - 68];
    } else if (t < 76 + G * G) {
        ww2s[t - 76] = Ww2[t - 76];
    }
    __syncthreads();

    // ---- P1: h1 = relu(bn(pos @ Wp1 + bp1)) -> fA bf16 (A-frag layout) ----
    {
        const int c = t & 127, hh = t >> 7;
        const float sc = gp1[c] * rsqrtf(1.f + EPS);
        const float w0 = Wp1[c] * sc, w1_ = Wp1[C + c] * sc, w2_ = Wp1[2 * C + c] * sc;
        const float bb = fmaf(bp1[c], sc, betap1[c]);
#pragma unroll
        for (int r2 = 0; r2 < 32; r2++) {
            const int r = hh * 32 + r2;
            float y = fmaf(pxs[r], w0, fmaf(pys[r], w1_, fmaf(pzs[r], w2_, bb)));
            y = y > 0.f ? y : 0.f;
            fA[r * 136 + c] = f2bf1(y);
        }
    }
    __syncthreads();

    // ---- P2: peb = h1 @ Wp2 (+bp2 via acc init) + PEB' = h1 @ Wp2' ----
    float4v acc[2][4];
    float4v pp = (float4v)0.f;
    {
        short8 Bf[2][4];
#pragma unroll
        for (int ct = 0; ct < 2; ct++) {
            const int cb = w * 2 + ct;
#pragma unroll
            for (int kk = 0; kk < 4; kk++)
                Bf[ct][kk] = *(const short8*)(PWp2 + (((cb * 4 + kk) * 4 + quad) * 16 + lan) * 8);
        }
        const float b0 = bp2[w * 32 + lan], b1 = bp2[w * 32 + 16 + lan];
#pragma unroll
        for (int q = 0; q < 4; q++) {
            acc[0][q] = (float4v)b0;
            acc[1][q] = (float4v)b1;
        }
#pragma unroll
        for (int q = 0; q < 4; q++)
#pragma unroll
            for (int kk = 0; kk < 4; kk++) {
                const short8 A = *(const short8*)(&fA[(q * 16 + lan) * 136 + kk * 32 + quad * 8]);
#pragma unroll
                for (int ct = 0; ct < 2; ct++)
                    acc[ct][q] = __builtin_amdgcn_mfma_f32_16x16x32_bf16(
                        A, Bf[ct][kk], acc[ct][q], 0, 0, 0);
            }
        // PEB': wave w -> rows [16w,16w+16)
#pragma unroll
        for (int kk = 0; kk < 4; kk++) {
            const short8 Bp = *(const short8*)(PWp2pb + ((kk * 4 + quad) * 16 + lan) * 8);
            const short8 A = *(const short8*)(&fA[(w * 16 + lan) * 136 + kk * 32 + quad * 8]);
            pp = __builtin_amdgcn_mfma_f32_16x16x32_bf16(A, Bp, pp, 0, 0, 0);
        }
    }
    __syncthreads();   // all h1 reads done

    // ---- P2b: scatter peb (bf16, in place) and PEB' (fp32) ----
    {
#pragma unroll
        for (int ct = 0; ct < 2; ct++)
#pragma unroll
            for (int q = 0; q < 4; q++)
#pragma unroll
                for (int reg = 0; reg < 4; reg++)
                    fA[(q * 16 + quad * 4 + reg) * 136 + w * 32 + ct * 16 + lan] =
                        f2bf1(acc[ct][q][reg]);
        if (lan < G) {
#pragma unroll
            for (int reg = 0; reg < 4; reg++)
                pebp[(w * 16 + quad * 4 + reg) * G + lan] = pp[reg];
        }
    }
    __syncthreads();

    // ---- P3: val = vg*mf + peb -> fA (in place); logits -> wl (ALL lanes) ----
    {
#pragma unroll
        for (int p = 0; p < 4; p++) {
            const int r = p * 16 + rsub;
            const float mf = mfr[p];
            frag_u peb, o;
            peb.v = *(const short8*)(&fA[r * 136 + c8]);
#pragma unroll
            for (int dd = 0; dd < 4; dd++) {
                const unsigned pv = peb.d[dd], vv = vg[p].d[dd];
                o.d[dd] = pk2(fmaf(bflo(vv), mf, bflo(pv)),
                              fmaf(bfhi(vv), mf, bfhi(pv)));
            }
            *(short8*)(&fA[r * 136 + c8]) = o.v;   // exclusive slot
        }
    }
    {
        // lane -> (query w, neighbor j, groups g0=2*quad, g1=g0+1)
        const int j = l & 15;
        const int r = (w << 4) + j;
        const float mf = idxs[r] >= 0 ? 1.f : 0.f;
        const int g0 = 2 * quad, g1 = g0 + 1;
        const float L0 = bf2f(kgs[r * G + g0]) * mf - qps[w * G + g0]
                       + pebp[r * G + g0] + cw1s[g0] + bw1[g0];
        const float L1 = bf2f(kgs[r * G + g1]) * mf - qps[w * G + g1]
                       + pebp[r * G + g1] + cw1s[g1] + bw1[g1];
        const float y0 = L0 * (gw1[g0] * rsqrtf(1.f + EPS)) + betaw1[g0];
        const float y1 = L1 * (gw1[g1] * rsqrtf(1.f + EPS)) + betaw1[g1];
        wl[w * 128 + j * 8 + g0] = y0 > 0.f ? y0 : 0.f;
        wl[w * 128 + j * 8 + g1] = y1 > 0.f ? y1 : 0.f;
    }
    __syncthreads();

    // ---- P5: a = hw@Ww2 + bw2; softmax over j (16-lane butterfly); *mask ----
    {
        const int j = l & 15;
        const int g0 = 2 * quad, g1 = g0 + 1;
        float hw_[8];
#pragma unroll
        for (int g = 0; g < 8; g++) hw_[g] = wl[w * 128 + j * 8 + g];
        float a0 = bw2[g0], a1 = bw2[g1];
#pragma unroll
        for (int g = 0; g < 8; g++) {
            a0 = fmaf(hw_[g], ww2s[g * 8 + g0], a0);
            a1 = fmaf(hw_[g], ww2s[g * 8 + g1], a1);
        }
        float mx0 = a0, mx1 = a1;
#pragma unroll
        for (int off = 1; off < 16; off <<= 1) {
            mx0 = fmaxf(mx0, __shfl_xor(mx0, off));
            mx1 = fmaxf(mx1, __shfl_xor(mx1, off));
        }
        const float e0 = __expf(a0 - mx0), e1 = __expf(a1 - mx1);
        float s0 = e0, s1 = e1;
#pragma unroll
        for (int off = 1; off < 16; off <<= 1) {
            s0 += __shfl_xor(s0, off);
            s1 += __shfl_xor(s1, off);
        }
        const float mf = idxs[(w << 4) + j] >= 0 ? 1.f : 0.f;
        // all wl reads above complete (wave-ordered DS) before these writes
        wl[w * 128 + j * 8 + g0] = e0 * (1.f / s0) * mf;
        wl[w * 128 + j * 8 + g1] = e1 * (1.f / s1) * mf;
    }
    __syncthreads();

    // ---- P6: out[q][c] = sum_j val[j][c] * w[j][c>>4] ----
#pragma unroll
    for (int i = 0; i < 2; i++) {
        const int e = t + 256 * i;
        const int q = e >> 7, c = e & 127, g = c >> 4;
        float a = 0.f;
#pragma unroll
        for (int j = 0; j < KNN; j++)
            a = fmaf(bf2f(fA[(q * 16 + j) * 136 + c]), wl[q * 128 + j * 8 + g], a);
        out[(size_t)(m0 + q) * C + c] = a;
    }
}

// ---------------------------------------------------------------------------
extern "C" void kernel_launch(void* const* d_in, const int* in_sizes, int n_in,
                              void* d_out, int out_size, void* d_ws, size_t ws_size,
                              hipStream_t stream)
{
    const float* query_feat    = (const float*)d_in[0];
    const float* context_feat  = (const float*)d_in[1];
    const float* query_coord   = (const float*)d_in[2];
    const float* context_coord = (const float*)d_in[3];
    const float* Wq    = (const float*)d_in[4];
    const float* bq    = (const float*)d_in[5];
    const float* gq    = (const float*)d_in[6];
    const float* betaq = (const float*)d_in[7];
    const float* Wk    = (const float*)d_in[8];
    const float* bk    = (const float*)d_in[9];
    const float* gk    = (const float*)d_in[10];
    const float* betak = (const float*)d_in[11];
    const float* Wv    = (const float*)d_in[12];
    const float* bv    = (const float*)d_in[13];
    const float* Wp1   = (const float*)d_in[14];
    const float* bp1   = (const float*)d_in[15];
    const float* gp1   = (const float*)d_in[16];
    const float* betap1= (const float*)d_in[17];
    const float* Wp2   = (const float*)d_in[18];
    const float* bp2   = (const float*)d_in[19];
    const float* Ww1   = (const float*)d_in[20];
    const float* bw1   = (const float*)d_in[21];
    const float* gw1   = (const float*)d_in[22];
    const float* betaw1= (const float*)d_in[23];
    const float* Ww2   = (const float*)d_in[24];
    const float* bw2   = (const float*)d_in[25];
    const int*   knn   = (const int*)d_in[26];

    const int M = in_sizes[0] / C;   // 16384
    const int N = in_sizes[1] / C;   // 131072

    // workspace: v (N*C bf16) | K' (N*G bf16) | Q' (M*G bf16) | prepped weights | cw1
    u16* vb = (u16*)d_ws;
    u16* Kp = vb + (size_t)N * C;
    u16* Qp = Kp + (size_t)N * G;
    u16* pw = Qp + (size_t)M * G;
    u16* pWk    = pw;
    u16* pWv    = pw + 16384;
    u16* pWq    = pw + 2 * 16384;
    u16* pWp2   = pw + 3 * 16384;
    u16* pWw1b  = pw + 4 * 16384;
    u16* pWp2pb = pw + 4 * 16384 + 4096;
    float* cw1  = (float*)(pw + 4 * 16384 + 2 * 4096);

    prep_w<<<18, 256, 0, stream>>>(Wk, Wv, Wq, Wp2, Ww1, bp2, pw, cw1);
    proj_all<<<N / 64 + M / 64, 256, 0, stream>>>(
        context_feat, query_feat,
        pWk, bk, gk, betak, pWv, bv,
        pWq, bq, gq, betaq, pWw1b,
        vb, Kp, Qp, N / 64);
    attn6<<<M / QB, 256, 0, stream>>>(vb, Kp, Qp, query_coord, context_coord,
                                      Wp1, bp1, gp1, betap1, pWp2, bp2,
                                      pWp2pb, cw1, bw1, gw1, betaw1, Ww2, bw2,
                                      knn, (float*)d_out);
}

// Round 5
// 209.847 us; speedup vs baseline: 1.0348x; 1.0217x over previous
//
#include <hip/hip_runtime.h>

#define C 128
#define G 8
#define KNN 16
#define QB 4
#define EPS 1e-5f

typedef unsigned short u16;
typedef __attribute__((ext_vector_type(8))) short short8;   // 8 bf16 = 4 VGPRs
typedef __attribute__((ext_vector_type(4))) float float4v;  // MFMA accumulator

union frag_u { short8 v; u16 u[8]; unsigned d[4]; };

__device__ inline u16 f2bf(float f) {
    unsigned u = __builtin_bit_cast(unsigned, f);
    unsigned r = (u + 0x7fffu + ((u >> 16) & 1u)) >> 16;
    return (u16)r;
}
__device__ inline float bf2f(u16 h) {
    unsigned u = ((unsigned)h) << 16;
    return __builtin_bit_cast(float, u);
}
// hardware packed f32->bf16 (RNE), 1 instr (guide T12 recipe, verified r3/r4)
__device__ inline unsigned pk2(float lo, float hi) {
    unsigned r;
    asm("v_cvt_pk_bf16_f32 %0, %1, %2" : "=v"(r) : "v"(lo), "v"(hi));
    return r;
}
__device__ inline u16 f2bf1(float f) { return (u16)pk2(f, f); }
__device__ inline float bflo(unsigned v) { return __builtin_bit_cast(float, v << 16); }
__device__ inline float bfhi(unsigned v) { return __builtin_bit_cast(float, v & 0xffff0000u); }

// ---------------------------------------------------------------------------
// Prep: swizzle weights into MFMA B-frag bf16 layout.  (identical to r4)
// ---------------------------------------------------------------------------
__global__ __launch_bounds__(256) void prep_w(
    const float* __restrict__ Wk, const float* __restrict__ Wv,
    const float* __restrict__ Wq, const float* __restrict__ Wp2,
    const float* __restrict__ Ww1, const float* __restrict__ bp2,
    u16* __restrict__ dst, float* __restrict__ cw1)
{
    __shared__ float w1s[C * G];
    const int b = blockIdx.x, t = threadIdx.x;
    if (b < 16) {
        const int mi = b >> 2, qt = b & 3;
        const float* W = mi == 0 ? Wk : mi == 1 ? Wv : mi == 2 ? Wq : Wp2;
        u16* d = dst + mi * 16384;
        for (int e = qt * 4096 + t; e < (qt + 1) * 4096; e += 256) {
            const int k = e >> 7, n = e & 127;
            const int cb = n >> 4, lan = n & 15;
            const int kk = k >> 5, quad = (k >> 3) & 3, j = k & 7;
            d[(((cb * 4 + kk) * 4 + quad) * 16 + lan) * 8 + j] = f2bf(W[e]);
        }
    } else if (b == 16) {
        u16* d = dst + 4 * 16384;
        for (int e = t; e < 4096; e += 256) {
            const int j = e & 7, lan = (e >> 3) & 15;
            const int quad = (e >> 7) & 3, kk = e >> 9;
            const int k = kk * 32 + quad * 8 + j;
            d[e] = lan < 8 ? f2bf(Ww1[k * G + lan]) : (u16)0;
        }
    } else {
        // Wp2' = Wp2 @ Ww1 -> B-frag; cw1 = bp2 @ Ww1   (Ww1 from LDS)
        u16* d = dst + 4 * 16384 + 4096;
        for (int e = t; e < 4096; e += 256) d[e] = 0;
        for (int e = t; e < C * G; e += 256) w1s[e] = Ww1[e];
        __syncthreads();
#pragma unroll
        for (int it = 0; it < 4; it++) {
            const int k = it * 32 + (t >> 3), g = t & 7;
            const float4* Wr = (const float4*)(Wp2 + k * C);
            float a = 0.f;
#pragma unroll 8
            for (int i4 = 0; i4 < 32; i4++) {
                const float4 wv = Wr[i4];
                a = fmaf(wv.x, w1s[(i4 * 4 + 0) * G + g], a);
                a = fmaf(wv.y, w1s[(i4 * 4 + 1) * G + g], a);
                a = fmaf(wv.z, w1s[(i4 * 4 + 2) * G + g], a);
                a = fmaf(wv.w, w1s[(i4 * 4 + 3) * G + g], a);
            }
            const int kk = k >> 5, quad = (k >> 3) & 3, j = k & 7;
            d[((kk * 4 + quad) * 16 + g) * 8 + j] = f2bf(a);
        }
        if (t < G) {
            float a = 0.f;
#pragma unroll 8
            for (int i = 0; i < C; i++) a = fmaf(bp2[i], w1s[i * G + t], a);
            cw1[t] = a;
        }
    }
}

// ---------------------------------------------------------------------------
// Fused projections, v2: r0 structure + verified local identities only:
//   staging via hw cvt_pk; bias folded into MFMA acc init (v,k,q);
//   BN epilogues folded to one fma; f2bf1 stores.
// Thread mapping, barriers, LDS layout identical to r0/r4.
// ---------------------------------------------------------------------------
__global__ __launch_bounds__(256) void proj_all(
    const float* __restrict__ Xc, const float* __restrict__ Xq,
    const u16* __restrict__ PWk, const float* __restrict__ bk,
    const float* __restrict__ gk, const float* __restrict__ betak,
    const u16* __restrict__ PWv, const float* __restrict__ bv,
    const u16* __restrict__ PWq, const float* __restrict__ bq,
    const float* __restrict__ gq, const float* __restrict__ betaq,
    const u16* __restrict__ PWw1b,
    u16* __restrict__ vout, u16* __restrict__ Kp, u16* __restrict__ Qp,
    int nkv)
{
    __shared__ u16 Xs[64 * 136];
    const int t = threadIdx.x;
    const int w = t >> 6, l = t & 63;
    const int quad = l >> 4, lan = l & 15;
    const bool isq = (int)blockIdx.x >= nkv;
    const long long row0 = (long long)(isq ? blockIdx.x - nkv : blockIdx.x) * 64;
    const float* X = isq ? Xq : Xc;

    // stage X tile -> bf16 LDS (hw cvt_pk)
    {
        const float4* Xv = (const float4*)(X + row0 * C);
#pragma unroll
        for (int i = 0; i < 8; i++) {
            const int e = t + 256 * i;
            const int r = e >> 5, c4 = e & 31;
            const float4 f = Xv[e];
            uint2 p;
            p.x = pk2(f.x, f.y);
            p.y = pk2(f.z, f.w);
            *(uint2*)(&Xs[r * 136 + c4 * 4]) = p;
        }
    }
    __syncthreads();

    if (!isq) {
        // ---- v pass (bias in acc init), packed bf16 in regs ----
        unsigned vp[2][4][2];
        {
            short8 Bf[2][4];
#pragma unroll
            for (int ct = 0; ct < 2; ct++) {
                const int cb = w * 2 + ct;
#pragma unroll
                for (int kk = 0; kk < 4; kk++)
                    Bf[ct][kk] = *(const short8*)(PWv + (((cb * 4 + kk) * 4 + quad) * 16 + lan) * 8);
            }
            const float b0v = bv[w * 32 + lan], b1v = bv[w * 32 + 16 + lan];
            float4v acc[2][4];
#pragma unroll
            for (int rt = 0; rt < 4; rt++) {
                acc[0][rt] = (float4v)b0v;
                acc[1][rt] = (float4v)b1v;
            }
#pragma unroll
            for (int rt = 0; rt < 4; rt++)
#pragma unroll
                for (int kk = 0; kk < 4; kk++) {
                    const short8 A = *(const short8*)(&Xs[(rt * 16 + lan) * 136 + kk * 32 + quad * 8]);
#pragma unroll
                    for (int ct = 0; ct < 2; ct++)
                        acc[ct][rt] = __builtin_amdgcn_mfma_f32_16x16x32_bf16(
                            A, Bf[ct][kk], acc[ct][rt], 0, 0, 0);
                }
#pragma unroll
            for (int ct = 0; ct < 2; ct++)
#pragma unroll
                for (int rt = 0; rt < 4; rt++)
#pragma unroll
                    for (int h = 0; h < 2; h++)
                        vp[ct][rt][h] = pk2(acc[ct][rt][2 * h], acc[ct][rt][2 * h + 1]);
        }
        // ---- k pass (bias in acc init), kept in regs ----
        float4v acck[2][4];
        {
            short8 Bf[2][4];
#pragma unroll
            for (int ct = 0; ct < 2; ct++) {
                const int cb = w * 2 + ct;
#pragma unroll
                for (int kk = 0; kk < 4; kk++)
                    Bf[ct][kk] = *(const short8*)(PWk + (((cb * 4 + kk) * 4 + quad) * 16 + lan) * 8);
            }
            const float b0k = bk[w * 32 + lan], b1k = bk[w * 32 + 16 + lan];
#pragma unroll
            for (int rt = 0; rt < 4; rt++) {
                acck[0][rt] = (float4v)b0k;
                acck[1][rt] = (float4v)b1k;
            }
#pragma unroll
            for (int rt = 0; rt < 4; rt++)
#pragma unroll
                for (int kk = 0; kk < 4; kk++) {
                    const short8 A = *(const short8*)(&Xs[(rt * 16 + lan) * 136 + kk * 32 + quad * 8]);
#pragma unroll
                    for (int ct = 0; ct < 2; ct++)
                        acck[ct][rt] = __builtin_amdgcn_mfma_f32_16x16x32_bf16(
                            A, Bf[ct][kk], acck[ct][rt], 0, 0, 0);
                }
        }
        __syncthreads();   // Xs A-reads done

        // k epilogue: y = fma(acc, sc, sh); relu -> Xs (row-major bf16)
#pragma unroll
        for (int ct = 0; ct < 2; ct++) {
            const int cg = w * 32 + ct * 16 + lan;
            const float sc = gk[cg] * rsqrtf(1.f + EPS);
            const float sh = betak[cg];
#pragma unroll
            for (int rt = 0; rt < 4; rt++)
#pragma unroll
                for (int reg = 0; reg < 4; reg++) {
                    float y = fmaf(acck[ct][rt][reg], sc, sh);
                    y = y > 0.f ? y : 0.f;
                    Xs[(rt * 16 + quad * 4 + reg) * 136 + cg] = f2bf1(y);
                }
        }
        __syncthreads();

        // K' = k @ Ww1 : wave w handles rows [16w,16w+16)
        {
            short8 Bw[4];
#pragma unroll
            for (int kk = 0; kk < 4; kk++)
                Bw[kk] = *(const short8*)(PWw1b + ((kk * 4 + quad) * 16 + lan) * 8);
            float4v ka = (float4v)0.f;
#pragma unroll
            for (int kk = 0; kk < 4; kk++) {
                const short8 A = *(const short8*)(&Xs[(w * 16 + lan) * 136 + kk * 32 + quad * 8]);
                ka = __builtin_amdgcn_mfma_f32_16x16x32_bf16(A, Bw[kk], ka, 0, 0, 0);
            }
            if (lan < G) {
#pragma unroll
                for (int reg = 0; reg < 4; reg++)
                    Kp[(row0 + w * 16 + quad * 4 + reg) * G + lan] = f2bf1(ka[reg]);
            }
        }
        __syncthreads();   // Xs K'-reads done

        // v epilogue (unpack) -> Xs -> coalesced store
#pragma unroll
        for (int ct = 0; ct < 2; ct++) {
            const int cg = w * 32 + ct * 16 + lan;
#pragma unroll
            for (int rt = 0; rt < 4; rt++)
#pragma unroll
                for (int h = 0; h < 2; h++) {
                    Xs[(rt * 16 + quad * 4 + 2 * h) * 136 + cg]     = (u16)(vp[ct][rt][h] & 0xffffu);
                    Xs[(rt * 16 + quad * 4 + 2 * h + 1) * 136 + cg] = (u16)(vp[ct][rt][h] >> 16);
                }
        }
        __syncthreads();
#pragma unroll
        for (int i = 0; i < 4; i++) {
            const int e = t + 256 * i;
            const int r = e >> 4, cc = (e & 15) * 8;
            *(short8*)(vout + (row0 + r) * C + cc) = *(const short8*)(&Xs[r * 136 + cc]);
        }
    } else {
        // ---- q path: bias in acc init; folded bn+relu; Q' = q@Ww1 ----
        float4v acc[2][4];
        {
            short8 Bf[2][4];
#pragma unroll
            for (int ct = 0; ct < 2; ct++) {
                const int cb = w * 2 + ct;
#pragma unroll
                for (int kk = 0; kk < 4; kk++)
                    Bf[ct][kk] = *(const short8*)(PWq + (((cb * 4 + kk) * 4 + quad) * 16 + lan) * 8);
            }
            const float b0q = bq[w * 32 + lan], b1q = bq[w * 32 + 16 + lan];
#pragma unroll
            for (int rt = 0; rt < 4; rt++) {
                acc[0][rt] = (float4v)b0q;
                acc[1][rt] = (float4v)b1q;
            }
#pragma unroll
            for (int rt = 0; rt < 4; rt++)
#pragma unroll
                for (int kk = 0; kk < 4; kk++) {
                    const short8 A = *(const short8*)(&Xs[(rt * 16 + lan) * 136 + kk * 32 + quad * 8]);
#pragma unroll
                    for (int ct = 0; ct < 2; ct++)
                        acc[ct][rt] = __builtin_amdgcn_mfma_f32_16x16x32_bf16(
                            A, Bf[ct][kk], acc[ct][rt], 0, 0, 0);
                }
        }
        __syncthreads();
#pragma unroll
        for (int ct = 0; ct < 2; ct++) {
            const int cg = w * 32 + ct * 16 + lan;
            const float sc = gq[cg] * rsqrtf(1.f + EPS);
            const float sh = betaq[cg];
#pragma unroll
            for (int rt = 0; rt < 4; rt++)
#pragma unroll
                for (int reg = 0; reg < 4; reg++) {
                    float y = fmaf(acc[ct][rt][reg], sc, sh);
                    y = y > 0.f ? y : 0.f;
                    Xs[(rt * 16 + quad * 4 + reg) * 136 + cg] = f2bf1(y);
                }
        }
        __syncthreads();
        {
            short8 Bw[4];
#pragma unroll
            for (int kk = 0; kk < 4; kk++)
                Bw[kk] = *(const short8*)(PWw1b + ((kk * 4 + quad) * 16 + lan) * 8);
            float4v qa = (float4v)0.f;
#pragma unroll
            for (int kk = 0; kk < 4; kk++) {
                const short8 A = *(const short8*)(&Xs[(w * 16 + lan) * 136 + kk * 32 + quad * 8]);
                qa = __builtin_amdgcn_mfma_f32_16x16x32_bf16(A, Bw[kk], qa, 0, 0, 0);
            }
            if (lan < G) {
#pragma unroll
                for (int reg = 0; reg < 4; reg++)
                    Qp[(row0 + w * 16 + quad * 4 + reg) * G + lan] = f2bf1(qa[reg]);
            }
        }
    }
}

// ---------------------------------------------------------------------------
// Attention v6.7 = verified v6.6 + paired-column P1 (b32 LDS writes, wave owns
// a row quarter) and paired-column P6 (b32 fA reads, float2 global store).
// Barriers, phase order, LDS layout all identical to v6.6.
// ---------------------------------------------------------------------------
__global__ __launch_bounds__(256) void attn6(
    const u16* __restrict__ vbuf, const u16* __restrict__ Kp,
    const u16* __restrict__ Qp,
    const float* __restrict__ qcoord, const float* __restrict__ ccoord,
    const float* __restrict__ Wp1, const float* __restrict__ bp1,
    const float* __restrict__ gp1, const float* __restrict__ betap1,
    const u16* __restrict__ PWp2, const float* __restrict__ bp2,
    const u16* __restrict__ PWp2pb, const float* __restrict__ cw1,
    const float* __restrict__ bw1,
    const float* __restrict__ gw1, const float* __restrict__ betaw1,
    const float* __restrict__ Ww2, const float* __restrict__ bw2,
    const int* __restrict__ knn, float* __restrict__ out)
{
    __shared__ u16   fA[64 * 136];    // h1 -> peb -> val
    __shared__ u16   kgs[64 * G];     // gathered K' rows (bf16)
    __shared__ float qps[QB * G];     // Q' rows (fp32)
    __shared__ float pebp[64 * G];    // PEB' (fp32)
    __shared__ float cw1s[G];
    __shared__ float ww2s[G * G];     // Ww2 staged once
    __shared__ float pxs[64], pys[64], pzs[64];
    __shared__ int   idxs[64];
    __shared__ float wl[QB * 16 * G]; // hw -> weights (in place)

    const int t = threadIdx.x;
    const int w = t >> 6, l = t & 63;
    const int quad = l >> 4, lan = l & 15;
    const int m0 = blockIdx.x * QB;
    const int rsub = t >> 4;
    const int c8 = (t & 15) * 8;

    // ---- P0: v prefetch (regs), indices, positions, K'/Q'/cw1/Ww2 to LDS ----
    float mfr[4];
    frag_u vg[4];
#pragma unroll
    for (int p = 0; p < 4; p++) {
        const int ii = knn[m0 * KNN + p * 16 + rsub];
        mfr[p] = ii >= 0 ? 1.f : 0.f;
        const size_t i0 = ii >= 0 ? ii : 0;
        vg[p].v = *(const short8*)(vbuf + i0 * C + c8);
    }
    if (t < 64) {
        const int q = t >> 4;
        const int ii = knn[m0 * KNN + t];
        const float mf = ii >= 0 ? 1.f : 0.f;
        const int i0 = ii >= 0 ? ii : 0;
        idxs[t] = ii;
        pxs[t] = (ccoord[i0 * 3 + 0] - qcoord[(m0 + q) * 3 + 0]) * mf;
        pys[t] = (ccoord[i0 * 3 + 1] - qcoord[(m0 + q) * 3 + 1]) * mf;
        pzs[t] = (ccoord[i0 * 3 + 2] - qcoord[(m0 + q) * 3 + 2]) * mf;
        *(short8*)(&kgs[t * G]) = *(const short8*)(Kp + (size_t)i0 * G);
    } else if (t < 68) {
        const int p = t - 64;
        frag_u qv;
        qv.v = *(const short8*)(Qp + (size_t)(m0 + p) * G);
#pragma unroll
        for (int j = 0; j < G; j++) qps[p * G + j] = bf2f(qv.u[j]);
    } else if (t < 76) {
        cw1s[t - 68] = cw1[t - 68];
    } else if (t < 76 + G * G) {
        ww2s[t - 76] = Ww2[t - 76];
    }
    __syncthreads();

    // ---- P1: h1 = relu(bn(pos @ Wp1 + bp1)) -> fA bf16 (paired cols) ----
    // thread: cols {2*(t&63), +1}; wave w: rows [16w, 16w+16)
    {
        const int pc = t & 63;
        const int c0 = 2 * pc;
        const float2 g2  = *(const float2*)(&gp1[c0]);
        const float2 b2  = *(const float2*)(&bp1[c0]);
        const float2 be2 = *(const float2*)(&betap1[c0]);
        const float2 wr0 = *(const float2*)(&Wp1[c0]);
        const float2 wr1 = *(const float2*)(&Wp1[C + c0]);
        const float2 wr2 = *(const float2*)(&Wp1[2 * C + c0]);
        const float rsq = rsqrtf(1.f + EPS);
        const float sc0 = g2.x * rsq, sc1 = g2.y * rsq;
        const float w00 = wr0.x * sc0, w01 = wr0.y * sc1;
        const float w10 = wr1.x * sc0, w11 = wr1.y * sc1;
        const float w20 = wr2.x * sc0, w21 = wr2.y * sc1;
        const float bb0 = fmaf(b2.x, sc0, be2.x);
        const float bb1 = fmaf(b2.y, sc1, be2.y);
#pragma unroll
        for (int r2 = 0; r2 < 16; r2++) {
            const int r = w * 16 + r2;
            const float x = pxs[r], y = pys[r], z = pzs[r];
            float ya = fmaf(x, w00, fmaf(y, w10, fmaf(z, w20, bb0)));
            float yb = fmaf(x, w01, fmaf(y, w11, fmaf(z, w21, bb1)));
            ya = ya > 0.f ? ya : 0.f;
            yb = yb > 0.f ? yb : 0.f;
            *(unsigned*)(&fA[r * 136 + c0]) = pk2(ya, yb);
        }
    }
    __syncthreads();

    // ---- P2: peb = h1 @ Wp2 (+bp2 via acc init) + PEB' = h1 @ Wp2' ----
    float4v acc[2][4];
    float4v pp = (float4v)0.f;
    {
        short8 Bf[2][4];
#pragma unroll
        for (int ct = 0; ct < 2; ct++) {
            const int cb = w * 2 + ct;
#pragma unroll
            for (int kk = 0; kk < 4; kk++)
                Bf[ct][kk] = *(const short8*)(PWp2 + (((cb * 4 + kk) * 4 + quad) * 16 + lan) * 8);
        }
        const float b0 = bp2[w * 32 + lan], b1 = bp2[w * 32 + 16 + lan];
#pragma unroll
        for (int q = 0; q < 4; q++) {
            acc[0][q] = (float4v)b0;
            acc[1][q] = (float4v)b1;
        }
#pragma unroll
        for (int q = 0; q < 4; q++)
#pragma unroll
            for (int kk = 0; kk < 4; kk++) {
                const short8 A = *(const short8*)(&fA[(q * 16 + lan) * 136 + kk * 32 + quad * 8]);
#pragma unroll
                for (int ct = 0; ct < 2; ct++)
                    acc[ct][q] = __builtin_amdgcn_mfma_f32_16x16x32_bf16(
                        A, Bf[ct][kk], acc[ct][q], 0, 0, 0);
            }
        // PEB': wave w -> rows [16w,16w+16)
#pragma unroll
        for (int kk = 0; kk < 4; kk++) {
            const short8 Bp = *(const short8*)(PWp2pb + ((kk * 4 + quad) * 16 + lan) * 8);
            const short8 A = *(const short8*)(&fA[(w * 16 + lan) * 136 + kk * 32 + quad * 8]);
            pp = __builtin_amdgcn_mfma_f32_16x16x32_bf16(A, Bp, pp, 0, 0, 0);
        }
    }
    __syncthreads();   // all h1 reads done

    // ---- P2b: scatter peb (bf16, in place) and PEB' (fp32) ----
    {
#pragma unroll
        for (int ct = 0; ct < 2; ct++)
#pragma unroll
            for (int q = 0; q < 4; q++)
#pragma unroll
                for (int reg = 0; reg < 4; reg++)
                    fA[(q * 16 + quad * 4 + reg) * 136 + w * 32 + ct * 16 + lan] =
                        f2bf1(acc[ct][q][reg]);
        if (lan < G) {
#pragma unroll
            for (int reg = 0; reg < 4; reg++)
                pebp[(w * 16 + quad * 4 + reg) * G + lan] = pp[reg];
        }
    }
    __syncthreads();

    // ---- P3: val = vg*mf + peb -> fA (in place); logits -> wl (ALL lanes) ----
    {
#pragma unroll
        for (int p = 0; p < 4; p++) {
            const int r = p * 16 + rsub;
            const float mf = mfr[p];
            frag_u peb, o;
            peb.v = *(const short8*)(&fA[r * 136 + c8]);
#pragma unroll
            for (int dd = 0; dd < 4; dd++) {
                const unsigned pv = peb.d[dd], vv = vg[p].d[dd];
                o.d[dd] = pk2(fmaf(bflo(vv), mf, bflo(pv)),
                              fmaf(bfhi(vv), mf, bfhi(pv)));
            }
            *(short8*)(&fA[r * 136 + c8]) = o.v;   // exclusive slot
        }
    }
    {
        // lane -> (query w, neighbor j, groups g0=2*quad, g1=g0+1)
        const int j = l & 15;
        const int r = (w << 4) + j;
        const float mf = idxs[r] >= 0 ? 1.f : 0.f;
        const int g0 = 2 * quad, g1 = g0 + 1;
        const float L0 = bf2f(kgs[r * G + g0]) * mf - qps[w * G + g0]
                       + pebp[r * G + g0] + cw1s[g0] + bw1[g0];
        const float L1 = bf2f(kgs[r * G + g1]) * mf - qps[w * G + g1]
                       + pebp[r * G + g1] + cw1s[g1] + bw1[g1];
        const float y0 = L0 * (gw1[g0] * rsqrtf(1.f + EPS)) + betaw1[g0];
        const float y1 = L1 * (gw1[g1] * rsqrtf(1.f + EPS)) + betaw1[g1];
        wl[w * 128 + j * 8 + g0] = y0 > 0.f ? y0 : 0.f;
        wl[w * 128 + j * 8 + g1] = y1 > 0.f ? y1 : 0.f;
    }
    __syncthreads();

    // ---- P5: a = hw@Ww2 + bw2; softmax over j (16-lane butterfly); *mask ----
    {
        const int j = l & 15;
        const int g0 = 2 * quad, g1 = g0 + 1;
        float hw_[8];
#pragma unroll
        for (int g = 0; g < 8; g++) hw_[g] = wl[w * 128 + j * 8 + g];
        float a0 = bw2[g0], a1 = bw2[g1];
#pragma unroll
        for (int g = 0; g < 8; g++) {
            a0 = fmaf(hw_[g], ww2s[g * 8 + g0], a0);
            a1 = fmaf(hw_[g], ww2s[g * 8 + g1], a1);
        }
        float mx0 = a0, mx1 = a1;
#pragma unroll
        for (int off = 1; off < 16; off <<= 1) {
            mx0 = fmaxf(mx0, __shfl_xor(mx0, off));
            mx1 = fmaxf(mx1, __shfl_xor(mx1, off));
        }
        const float e0 = __expf(a0 - mx0), e1 = __expf(a1 - mx1);
        float s0 = e0, s1 = e1;
#pragma unroll
        for (int off = 1; off < 16; off <<= 1) {
            s0 += __shfl_xor(s0, off);
            s1 += __shfl_xor(s1, off);
        }
        const float mf = idxs[(w << 4) + j] >= 0 ? 1.f : 0.f;
        wl[w * 128 + j * 8 + g0] = e0 * (1.f / s0) * mf;
        wl[w * 128 + j * 8 + g1] = e1 * (1.f / s1) * mf;
    }
    __syncthreads();

    // ---- P6: out[q][c] = sum_j val[j][c] * w[j][c>>4]  (paired cols) ----
    {
        const int q = t >> 6;            // wave = query
        const int pc = t & 63;
        const int c0 = 2 * pc;
        const int g = pc >> 3;           // (2*pc)>>4
        float s0 = 0.f, s1 = 0.f;
#pragma unroll
        for (int j = 0; j < KNN; j++) {
            const unsigned v = *(const unsigned*)(&fA[(q * 16 + j) * 136 + c0]);
            const float wv = wl[q * 128 + j * 8 + g];
            s0 = fmaf(bflo(v), wv, s0);
            s1 = fmaf(bfhi(v), wv, s1);
        }
        *(float2*)(&out[(size_t)(m0 + q) * C + c0]) = make_float2(s0, s1);
    }
}

// ---------------------------------------------------------------------------
extern "C" void kernel_launch(void* const* d_in, const int* in_sizes, int n_in,
                              void* d_out, int out_size, void* d_ws, size_t ws_size,
                              hipStream_t stream)
{
    const float* query_feat    = (const float*)d_in[0];
    const float* context_feat  = (const float*)d_in[1];
    const float* query_coord   = (const float*)d_in[2];
    const float* context_coord = (const float*)d_in[3];
    const float* Wq    = (const float*)d_in[4];
    const float* bq    = (const float*)d_in[5];
    const float* gq    = (const float*)d_in[6];
    const float* betaq = (const float*)d_in[7];
    const float* Wk    = (const float*)d_in[8];
    const float* bk    = (const float*)d_in[9];
    const float* gk    = (const float*)d_in[10];
    const float* betak = (const float*)d_in[11];
    const float* Wv    = (const float*)d_in[12];
    const float* bv    = (const float*)d_in[13];
    const float* Wp1   = (const float*)d_in[14];
    const float* bp1   = (const float*)d_in[15];
    const float* gp1   = (const float*)d_in[16];
    const float* betap1= (const float*)d_in[17];
    const float* Wp2   = (const float*)d_in[18];
    const float* bp2   = (const float*)d_in[19];
    const float* Ww1   = (const float*)d_in[20];
    const float* bw1   = (const float*)d_in[21];
    const float* gw1   = (const float*)d_in[22];
    const float* betaw1= (const float*)d_in[23];
    const float* Ww2   = (const float*)d_in[24];
    const float* bw2   = (const float*)d_in[25];
    const int*   knn   = (const int*)d_in[26];

    const int M = in_sizes[0] / C;   // 16384
    const int N = in_sizes[1] / C;   // 131072

    // workspace: v (N*C bf16) | K' (N*G bf16) | Q' (M*G bf16) | prepped weights | cw1
    u16* vb = (u16*)d_ws;
    u16* Kp = vb + (size_t)N * C;
    u16* Qp = Kp + (size_t)N * G;
    u16* pw = Qp + (size_t)M * G;
    u16* pWk    = pw;
    u16* pWv    = pw + 16384;
    u16* pWq    = pw + 2 * 16384;
    u16* pWp2   = pw + 3 * 16384;
    u16* pWw1b  = pw + 4 * 16384;
    u16* pWp2pb = pw + 4 * 16384 + 4096;
    float* cw1  = (float*)(pw + 4 * 16384 + 2 * 4096);

    prep_w<<<18, 256, 0, stream>>>(Wk, Wv, Wq, Wp2, Ww1, bp2, pw, cw1);
    proj_all<<<N / 64 + M / 64, 256, 0, stream>>>(
        context_feat, query_feat,
        pWk, bk, gk, betak, pWv, bv,
        pWq, bq, gq, betaq, pWw1b,
        vb, Kp, Qp, N / 64);
    attn6<<<M / QB, 256, 0, stream>>>(vb, Kp, Qp, query_coord, context_coord,
                                      Wp1, bp1, gp1, betap1, pWp2, bp2,
                                      pWp2pb, cw1, bw1, gw1, betaw1, Ww2, bw2,
                                      knn, (float*)d_out);
}

// Round 6
// 209.559 us; speedup vs baseline: 1.0362x; 1.0014x over previous
//
#include <hip/hip_runtime.h>

#define C 128
#define G 8
#define KNN 16
#define QB 8
#define EPS 1e-5f

typedef unsigned short u16;
typedef __attribute__((ext_vector_type(8))) short short8;   // 8 bf16 = 4 VGPRs
typedef __attribute__((ext_vector_type(4))) float float4v;  // MFMA accumulator

union frag_u { short8 v; u16 u[8]; unsigned d[4]; };

__device__ inline u16 f2bf(float f) {
    unsigned u = __builtin_bit_cast(unsigned, f);
    unsigned r = (u + 0x7fffu + ((u >> 16) & 1u)) >> 16;
    return (u16)r;
}
__device__ inline float bf2f(u16 h) {
    unsigned u = ((unsigned)h) << 16;
    return __builtin_bit_cast(float, u);
}
// hardware packed f32->bf16 (RNE), 1 instr (guide T12 recipe, verified r3-r5)
__device__ inline unsigned pk2(float lo, float hi) {
    unsigned r;
    asm("v_cvt_pk_bf16_f32 %0, %1, %2" : "=v"(r) : "v"(lo), "v"(hi));
    return r;
}
__device__ inline u16 f2bf1(float f) { return (u16)pk2(f, f); }
__device__ inline float bflo(unsigned v) { return __builtin_bit_cast(float, v << 16); }
__device__ inline float bfhi(unsigned v) { return __builtin_bit_cast(float, v & 0xffff0000u); }

// ---------------------------------------------------------------------------
// Prep: swizzle weights into MFMA B-frag bf16 layout.  (identical to r5)
// ---------------------------------------------------------------------------
__global__ __launch_bounds__(256) void prep_w(
    const float* __restrict__ Wk, const float* __restrict__ Wv,
    const float* __restrict__ Wq, const float* __restrict__ Wp2,
    const float* __restrict__ Ww1, const float* __restrict__ bp2,
    u16* __restrict__ dst, float* __restrict__ cw1)
{
    __shared__ float w1s[C * G];
    const int b = blockIdx.x, t = threadIdx.x;
    if (b < 16) {
        const int mi = b >> 2, qt = b & 3;
        const float* W = mi == 0 ? Wk : mi == 1 ? Wv : mi == 2 ? Wq : Wp2;
        u16* d = dst + mi * 16384;
        for (int e = qt * 4096 + t; e < (qt + 1) * 4096; e += 256) {
            const int k = e >> 7, n = e & 127;
            const int cb = n >> 4, lan = n & 15;
            const int kk = k >> 5, quad = (k >> 3) & 3, j = k & 7;
            d[(((cb * 4 + kk) * 4 + quad) * 16 + lan) * 8 + j] = f2bf(W[e]);
        }
    } else if (b == 16) {
        u16* d = dst + 4 * 16384;
        for (int e = t; e < 4096; e += 256) {
            const int j = e & 7, lan = (e >> 3) & 15;
            const int quad = (e >> 7) & 3, kk = e >> 9;
            const int k = kk * 32 + quad * 8 + j;
            d[e] = lan < 8 ? f2bf(Ww1[k * G + lan]) : (u16)0;
        }
    } else {
        // Wp2' = Wp2 @ Ww1 -> B-frag; cw1 = bp2 @ Ww1   (Ww1 from LDS)
        u16* d = dst + 4 * 16384 + 4096;
        for (int e = t; e < 4096; e += 256) d[e] = 0;
        for (int e = t; e < C * G; e += 256) w1s[e] = Ww1[e];
        __syncthreads();
#pragma unroll
        for (int it = 0; it < 4; it++) {
            const int k = it * 32 + (t >> 3), g = t & 7;
            const float4* Wr = (const float4*)(Wp2 + k * C);
            float a = 0.f;
#pragma unroll 8
            for (int i4 = 0; i4 < 32; i4++) {
                const float4 wv = Wr[i4];
                a = fmaf(wv.x, w1s[(i4 * 4 + 0) * G + g], a);
                a = fmaf(wv.y, w1s[(i4 * 4 + 1) * G + g], a);
                a = fmaf(wv.z, w1s[(i4 * 4 + 2) * G + g], a);
                a = fmaf(wv.w, w1s[(i4 * 4 + 3) * G + g], a);
            }
            const int kk = k >> 5, quad = (k >> 3) & 3, j = k & 7;
            d[((kk * 4 + quad) * 16 + g) * 8 + j] = f2bf(a);
        }
        if (t < G) {
            float a = 0.f;
#pragma unroll 8
            for (int i = 0; i < C; i++) a = fmaf(bp2[i], w1s[i * G + t], a);
            cw1[t] = a;
        }
    }
}

// ---------------------------------------------------------------------------
// Fused projections.  (identical to r5)
// ---------------------------------------------------------------------------
__global__ __launch_bounds__(256) void proj_all(
    const float* __restrict__ Xc, const float* __restrict__ Xq,
    const u16* __restrict__ PWk, const float* __restrict__ bk,
    const float* __restrict__ gk, const float* __restrict__ betak,
    const u16* __restrict__ PWv, const float* __restrict__ bv,
    const u16* __restrict__ PWq, const float* __restrict__ bq,
    const float* __restrict__ gq, const float* __restrict__ betaq,
    const u16* __restrict__ PWw1b,
    u16* __restrict__ vout, u16* __restrict__ Kp, u16* __restrict__ Qp,
    int nkv)
{
    __shared__ u16 Xs[64 * 136];
    const int t = threadIdx.x;
    const int w = t >> 6, l = t & 63;
    const int quad = l >> 4, lan = l & 15;
    const bool isq = (int)blockIdx.x >= nkv;
    const long long row0 = (long long)(isq ? blockIdx.x - nkv : blockIdx.x) * 64;
    const float* X = isq ? Xq : Xc;

    // stage X tile -> bf16 LDS (hw cvt_pk)
    {
        const float4* Xv = (const float4*)(X + row0 * C);
#pragma unroll
        for (int i = 0; i < 8; i++) {
            const int e = t + 256 * i;
            const int r = e >> 5, c4 = e & 31;
            const float4 f = Xv[e];
            uint2 p;
            p.x = pk2(f.x, f.y);
            p.y = pk2(f.z, f.w);
            *(uint2*)(&Xs[r * 136 + c4 * 4]) = p;
        }
    }
    __syncthreads();

    if (!isq) {
        // ---- v pass (bias in acc init), packed bf16 in regs ----
        unsigned vp[2][4][2];
        {
            short8 Bf[2][4];
#pragma unroll
            for (int ct = 0; ct < 2; ct++) {
                const int cb = w * 2 + ct;
#pragma unroll
                for (int kk = 0; kk < 4; kk++)
                    Bf[ct][kk] = *(const short8*)(PWv + (((cb * 4 + kk) * 4 + quad) * 16 + lan) * 8);
            }
            const float b0v = bv[w * 32 + lan], b1v = bv[w * 32 + 16 + lan];
            float4v acc[2][4];
#pragma unroll
            for (int rt = 0; rt < 4; rt++) {
                acc[0][rt] = (float4v)b0v;
                acc[1][rt] = (float4v)b1v;
            }
#pragma unroll
            for (int rt = 0; rt < 4; rt++)
#pragma unroll
                for (int kk = 0; kk < 4; kk++) {
                    const short8 A = *(const short8*)(&Xs[(rt * 16 + lan) * 136 + kk * 32 + quad * 8]);
#pragma unroll
                    for (int ct = 0; ct < 2; ct++)
                        acc[ct][rt] = __builtin_amdgcn_mfma_f32_16x16x32_bf16(
                            A, Bf[ct][kk], acc[ct][rt], 0, 0, 0);
                }
#pragma unroll
            for (int ct = 0; ct < 2; ct++)
#pragma unroll
                for (int rt = 0; rt < 4; rt++)
#pragma unroll
                    for (int h = 0; h < 2; h++)
                        vp[ct][rt][h] = pk2(acc[ct][rt][2 * h], acc[ct][rt][2 * h + 1]);
        }
        // ---- k pass (bias in acc init), kept in regs ----
        float4v acck[2][4];
        {
            short8 Bf[2][4];
#pragma unroll
            for (int ct = 0; ct < 2; ct++) {
                const int cb = w * 2 + ct;
#pragma unroll
                for (int kk = 0; kk < 4; kk++)
                    Bf[ct][kk] = *(const short8*)(PWk + (((cb * 4 + kk) * 4 + quad) * 16 + lan) * 8);
            }
            const float b0k = bk[w * 32 + lan], b1k = bk[w * 32 + 16 + lan];
#pragma unroll
            for (int rt = 0; rt < 4; rt++) {
                acck[0][rt] = (float4v)b0k;
                acck[1][rt] = (float4v)b1k;
            }
#pragma unroll
            for (int rt = 0; rt < 4; rt++)
#pragma unroll
                for (int kk = 0; kk < 4; kk++) {
                    const short8 A = *(const short8*)(&Xs[(rt * 16 + lan) * 136 + kk * 32 + quad * 8]);
#pragma unroll
                    for (int ct = 0; ct < 2; ct++)
                        acck[ct][rt] = __builtin_amdgcn_mfma_f32_16x16x32_bf16(
                            A, Bf[ct][kk], acck[ct][rt], 0, 0, 0);
                }
        }
        __syncthreads();   // Xs A-reads done

        // k epilogue: y = fma(acc, sc, sh); relu -> Xs (row-major bf16)
#pragma unroll
        for (int ct = 0; ct < 2; ct++) {
            const int cg = w * 32 + ct * 16 + lan;
            const float sc = gk[cg] * rsqrtf(1.f + EPS);
            const float sh = betak[cg];
#pragma unroll
            for (int rt = 0; rt < 4; rt++)
#pragma unroll
                for (int reg = 0; reg < 4; reg++) {
                    float y = fmaf(acck[ct][rt][reg], sc, sh);
                    y = y > 0.f ? y : 0.f;
                    Xs[(rt * 16 + quad * 4 + reg) * 136 + cg] = f2bf1(y);
                }
        }
        __syncthreads();

        // K' = k @ Ww1 : wave w handles rows [16w,16w+16)
        {
            short8 Bw[4];
#pragma unroll
            for (int kk = 0; kk < 4; kk++)
                Bw[kk] = *(const short8*)(PWw1b + ((kk * 4 + quad) * 16 + lan) * 8);
            float4v ka = (float4v)0.f;
#pragma unroll
            for (int kk = 0; kk < 4; kk++) {
                const short8 A = *(const short8*)(&Xs[(w * 16 + lan) * 136 + kk * 32 + quad * 8]);
                ka = __builtin_amdgcn_mfma_f32_16x16x32_bf16(A, Bw[kk], ka, 0, 0, 0);
            }
            if (lan < G) {
#pragma unroll
                for (int reg = 0; reg < 4; reg++)
                    Kp[(row0 + w * 16 + quad * 4 + reg) * G + lan] = f2bf1(ka[reg]);
            }
        }
        __syncthreads();   // Xs K'-reads done

        // v epilogue (unpack) -> Xs -> coalesced store
#pragma unroll
        for (int ct = 0; ct < 2; ct++) {
            const int cg = w * 32 + ct * 16 + lan;
#pragma unroll
            for (int rt = 0; rt < 4; rt++)
#pragma unroll
                for (int h = 0; h < 2; h++) {
                    Xs[(rt * 16 + quad * 4 + 2 * h) * 136 + cg]     = (u16)(vp[ct][rt][h] & 0xffffu);
                    Xs[(rt * 16 + quad * 4 + 2 * h + 1) * 136 + cg] = (u16)(vp[ct][rt][h] >> 16);
                }
        }
        __syncthreads();
#pragma unroll
        for (int i = 0; i < 4; i++) {
            const int e = t + 256 * i;
            const int r = e >> 4, cc = (e & 15) * 8;
            *(short8*)(vout + (row0 + r) * C + cc) = *(const short8*)(&Xs[r * 136 + cc]);
        }
    } else {
        // ---- q path: bias in acc init; folded bn+relu; Q' = q@Ww1 ----
        float4v acc[2][4];
        {
            short8 Bf[2][4];
#pragma unroll
            for (int ct = 0; ct < 2; ct++) {
                const int cb = w * 2 + ct;
#pragma unroll
                for (int kk = 0; kk < 4; kk++)
                    Bf[ct][kk] = *(const short8*)(PWq + (((cb * 4 + kk) * 4 + quad) * 16 + lan) * 8);
            }
            const float b0q = bq[w * 32 + lan], b1q = bq[w * 32 + 16 + lan];
#pragma unroll
            for (int rt = 0; rt < 4; rt++) {
                acc[0][rt] = (float4v)b0q;
                acc[1][rt] = (float4v)b1q;
            }
#pragma unroll
            for (int rt = 0; rt < 4; rt++)
#pragma unroll
                for (int kk = 0; kk < 4; kk++) {
                    const short8 A = *(const short8*)(&Xs[(rt * 16 + lan) * 136 + kk * 32 + quad * 8]);
#pragma unroll
                    for (int ct = 0; ct < 2; ct++)
                        acc[ct][rt] = __builtin_amdgcn_mfma_f32_16x16x32_bf16(
                            A, Bf[ct][kk], acc[ct][rt], 0, 0, 0);
                }
        }
        __syncthreads();
#pragma unroll
        for (int ct = 0; ct < 2; ct++) {
            const int cg = w * 32 + ct * 16 + lan;
            const float sc = gq[cg] * rsqrtf(1.f + EPS);
            const float sh = betaq[cg];
#pragma unroll
            for (int rt = 0; rt < 4; rt++)
#pragma unroll
                for (int reg = 0; reg < 4; reg++) {
                    float y = fmaf(acc[ct][rt][reg], sc, sh);
                    y = y > 0.f ? y : 0.f;
                    Xs[(rt * 16 + quad * 4 + reg) * 136 + cg] = f2bf1(y);
                }
        }
        __syncthreads();
        {
            short8 Bw[4];
#pragma unroll
            for (int kk = 0; kk < 4; kk++)
                Bw[kk] = *(const short8*)(PWw1b + ((kk * 4 + quad) * 16 + lan) * 8);
            float4v qa = (float4v)0.f;
#pragma unroll
            for (int kk = 0; kk < 4; kk++) {
                const short8 A = *(const short8*)(&Xs[(w * 16 + lan) * 136 + kk * 32 + quad * 8]);
                qa = __builtin_amdgcn_mfma_f32_16x16x32_bf16(A, Bw[kk], qa, 0, 0, 0);
            }
            if (lan < G) {
#pragma unroll
                for (int reg = 0; reg < 4; reg++)
                    Qp[(row0 + w * 16 + quad * 4 + reg) * G + lan] = f2bf1(qa[reg]);
            }
        }
    }
}

// ---------------------------------------------------------------------------
// Attention v6.8 = verified v6.7 scaled to QB=8 (128 neighbor rows / block):
// identical phase order, barriers, and inner math; trip counts doubled.
// + pos packed float4 in LDS (b128 broadcast reads); Bp[4] hoisted.
// ---------------------------------------------------------------------------
__global__ __launch_bounds__(256) void attn6(
    const u16* __restrict__ vbuf, const u16* __restrict__ Kp,
    const u16* __restrict__ Qp,
    const float* __restrict__ qcoord, const float* __restrict__ ccoord,
    const float* __restrict__ Wp1, const float* __restrict__ bp1,
    const float* __restrict__ gp1, const float* __restrict__ betap1,
    const u16* __restrict__ PWp2, const float* __restrict__ bp2,
    const u16* __restrict__ PWp2pb, const float* __restrict__ cw1,
    const float* __restrict__ bw1,
    const float* __restrict__ gw1, const float* __restrict__ betaw1,
    const float* __restrict__ Ww2, const float* __restrict__ bw2,
    const int* __restrict__ knn, float* __restrict__ out)
{
    __shared__ u16   fA[128 * 136];     // h1 -> peb -> val (34.8 KB)
    __shared__ u16   kgs[128 * G];      // gathered K' rows (bf16)
    __shared__ float qps[QB * G];       // Q' rows (fp32)
    __shared__ float pebp[128 * G];     // PEB' (fp32)
    __shared__ float cw1s[G];
    __shared__ float ww2s[G * G];       // Ww2 staged once
    __shared__ float4 ps4[128];         // packed pos (x,y,z,0)
    __shared__ int   idxs[128];
    __shared__ float wl[QB * 16 * G];   // hw -> weights (in place)

    const int t = threadIdx.x;
    const int w = t >> 6, l = t & 63;
    const int quad = l >> 4, lan = l & 15;
    const int m0 = blockIdx.x * QB;
    const int rsub = t >> 4;
    const int c8 = (t & 15) * 8;

    // ---- P0: v prefetch (regs), indices, positions, K'/Q'/cw1/Ww2 to LDS ----
    float mfr[8];
    frag_u vg[8];
#pragma unroll
    for (int p = 0; p < 8; p++) {
        const int ii = knn[m0 * KNN + p * 16 + rsub];
        mfr[p] = ii >= 0 ? 1.f : 0.f;
        const size_t i0 = ii >= 0 ? ii : 0;
        vg[p].v = *(const short8*)(vbuf + i0 * C + c8);
    }
    if (t < 128) {
        const int q = t >> 4;
        const int ii = knn[m0 * KNN + t];
        const float mf = ii >= 0 ? 1.f : 0.f;
        const int i0 = ii >= 0 ? ii : 0;
        idxs[t] = ii;
        float4 p4;
        p4.x = (ccoord[i0 * 3 + 0] - qcoord[(m0 + q) * 3 + 0]) * mf;
        p4.y = (ccoord[i0 * 3 + 1] - qcoord[(m0 + q) * 3 + 1]) * mf;
        p4.z = (ccoord[i0 * 3 + 2] - qcoord[(m0 + q) * 3 + 2]) * mf;
        p4.w = 0.f;
        ps4[t] = p4;
        *(short8*)(&kgs[t * G]) = *(const short8*)(Kp + (size_t)i0 * G);
    } else if (t < 128 + QB) {
        const int p = t - 128;
        frag_u qv;
        qv.v = *(const short8*)(Qp + (size_t)(m0 + p) * G);
#pragma unroll
        for (int j = 0; j < G; j++) qps[p * G + j] = bf2f(qv.u[j]);
    } else if (t < 136 + G) {
        cw1s[t - 136] = cw1[t - 136];
    } else if (t < 144 + G * G) {
        ww2s[t - 144] = Ww2[t - 144];
    }
    __syncthreads();

    // ---- P1: h1 = relu(bn(pos @ Wp1 + bp1)) -> fA bf16 (paired cols) ----
    // thread: cols {2*(t&63), +1}; wave w: rows [32w, 32w+32)
    {
        const int pc = t & 63;
        const int c0 = 2 * pc;
        const float2 g2  = *(const float2*)(&gp1[c0]);
        const float2 b2  = *(const float2*)(&bp1[c0]);
        const float2 be2 = *(const float2*)(&betap1[c0]);
        const float2 wr0 = *(const float2*)(&Wp1[c0]);
        const float2 wr1 = *(const float2*)(&Wp1[C + c0]);
        const float2 wr2 = *(const float2*)(&Wp1[2 * C + c0]);
        const float rsq = rsqrtf(1.f + EPS);
        const float sc0 = g2.x * rsq, sc1 = g2.y * rsq;
        const float w00 = wr0.x * sc0, w01 = wr0.y * sc1;
        const float w10 = wr1.x * sc0, w11 = wr1.y * sc1;
        const float w20 = wr2.x * sc0, w21 = wr2.y * sc1;
        const float bb0 = fmaf(b2.x, sc0, be2.x);
        const float bb1 = fmaf(b2.y, sc1, be2.y);
#pragma unroll
        for (int r2 = 0; r2 < 32; r2++) {
            const int r = w * 32 + r2;
            const float4 p4 = ps4[r];
            float ya = fmaf(p4.x, w00, fmaf(p4.y, w10, fmaf(p4.z, w20, bb0)));
            float yb = fmaf(p4.x, w01, fmaf(p4.y, w11, fmaf(p4.z, w21, bb1)));
            ya = ya > 0.f ? ya : 0.f;
            yb = yb > 0.f ? yb : 0.f;
            *(unsigned*)(&fA[r * 136 + c0]) = pk2(ya, yb);
        }
    }
    __syncthreads();

    // ---- P2: peb = h1 @ Wp2 (+bp2 via acc init) + PEB' = h1 @ Wp2' ----
    float4v acc[2][8];
    float4v pp0 = (float4v)0.f, pp1 = (float4v)0.f;
    {
        short8 Bf[2][4];
#pragma unroll
        for (int ct = 0; ct < 2; ct++) {
            const int cb = w * 2 + ct;
#pragma unroll
            for (int kk = 0; kk < 4; kk++)
                Bf[ct][kk] = *(const short8*)(PWp2 + (((cb * 4 + kk) * 4 + quad) * 16 + lan) * 8);
        }
        const float b0 = bp2[w * 32 + lan], b1 = bp2[w * 32 + 16 + lan];
#pragma unroll
        for (int q = 0; q < 8; q++) {
            acc[0][q] = (float4v)b0;
            acc[1][q] = (float4v)b1;
        }
#pragma unroll
        for (int q = 0; q < 8; q++)
#pragma unroll
            for (int kk = 0; kk < 4; kk++) {
                const short8 A = *(const short8*)(&fA[(q * 16 + lan) * 136 + kk * 32 + quad * 8]);
#pragma unroll
                for (int ct = 0; ct < 2; ct++)
                    acc[ct][q] = __builtin_amdgcn_mfma_f32_16x16x32_bf16(
                        A, Bf[ct][kk], acc[ct][q], 0, 0, 0);
            }
        // PEB': wave w -> row tiles w and w+4 (Bp hoisted, reused)
        short8 Bp[4];
#pragma unroll
        for (int kk = 0; kk < 4; kk++)
            Bp[kk] = *(const short8*)(PWp2pb + ((kk * 4 + quad) * 16 + lan) * 8);
#pragma unroll
        for (int kk = 0; kk < 4; kk++) {
            const short8 A0 = *(const short8*)(&fA[(w * 16 + lan) * 136 + kk * 32 + quad * 8]);
            pp0 = __builtin_amdgcn_mfma_f32_16x16x32_bf16(A0, Bp[kk], pp0, 0, 0, 0);
            const short8 A1 = *(const short8*)(&fA[((w + 4) * 16 + lan) * 136 + kk * 32 + quad * 8]);
            pp1 = __builtin_amdgcn_mfma_f32_16x16x32_bf16(A1, Bp[kk], pp1, 0, 0, 0);
        }
    }
    __syncthreads();   // all h1 reads done

    // ---- P2b: scatter peb (bf16, in place) and PEB' (fp32) ----
    {
#pragma unroll
        for (int ct = 0; ct < 2; ct++)
#pragma unroll
            for (int q = 0; q < 8; q++)
#pragma unroll
                for (int reg = 0; reg < 4; reg++)
                    fA[(q * 16 + quad * 4 + reg) * 136 + w * 32 + ct * 16 + lan] =
                        f2bf1(acc[ct][q][reg]);
        if (lan < G) {
#pragma unroll
            for (int reg = 0; reg < 4; reg++) {
                pebp[(w * 16 + quad * 4 + reg) * G + lan] = pp0[reg];
                pebp[((w + 4) * 16 + quad * 4 + reg) * G + lan] = pp1[reg];
            }
        }
    }
    __syncthreads();

    // ---- P3: val = vg*mf + peb -> fA (in place); logits -> wl (ALL lanes) ----
    {
#pragma unroll
        for (int p = 0; p < 8; p++) {
            const int r = p * 16 + rsub;
            const float mf = mfr[p];
            frag_u peb, o;
            peb.v = *(const short8*)(&fA[r * 136 + c8]);
#pragma unroll
            for (int dd = 0; dd < 4; dd++) {
                const unsigned pv = peb.d[dd], vv = vg[p].d[dd];
                o.d[dd] = pk2(fmaf(bflo(vv), mf, bflo(pv)),
                              fmaf(bfhi(vv), mf, bfhi(pv)));
            }
            *(short8*)(&fA[r * 136 + c8]) = o.v;   // exclusive slot
        }
    }
    {
        // lane -> (query 4*qq+w, neighbor j, groups g0=2*quad, g1=g0+1)
        const int j = l & 15;
        const int g0 = 2 * quad, g1 = g0 + 1;
        const float scw0 = gw1[g0] * rsqrtf(1.f + EPS);
        const float scw1 = gw1[g1] * rsqrtf(1.f + EPS);
#pragma unroll
        for (int qq = 0; qq < 2; qq++) {
            const int q = 4 * qq + w;
            const int r = (q << 4) + j;
            const float mf = idxs[r] >= 0 ? 1.f : 0.f;
            const float L0 = bf2f(kgs[r * G + g0]) * mf - qps[q * G + g0]
                           + pebp[r * G + g0] + cw1s[g0] + bw1[g0];
            const float L1 = bf2f(kgs[r * G + g1]) * mf - qps[q * G + g1]
                           + pebp[r * G + g1] + cw1s[g1] + bw1[g1];
            const float y0 = L0 * scw0 + betaw1[g0];
            const float y1 = L1 * scw1 + betaw1[g1];
            wl[q * 128 + j * 8 + g0] = y0 > 0.f ? y0 : 0.f;
            wl[q * 128 + j * 8 + g1] = y1 > 0.f ? y1 : 0.f;
        }
    }
    __syncthreads();

    // ---- P5: a = hw@Ww2 + bw2; softmax over j (16-lane butterfly); *mask ----
    {
        const int j = l & 15;
        const int g0 = 2 * quad, g1 = g0 + 1;
        const float bb0 = bw2[g0], bb1 = bw2[g1];
#pragma unroll
        for (int qq = 0; qq < 2; qq++) {
            const int q = 4 * qq + w;
            float hw_[8];
#pragma unroll
            for (int g = 0; g < 8; g++) hw_[g] = wl[q * 128 + j * 8 + g];
            float a0 = bb0, a1 = bb1;
#pragma unroll
            for (int g = 0; g < 8; g++) {
                a0 = fmaf(hw_[g], ww2s[g * 8 + g0], a0);
                a1 = fmaf(hw_[g], ww2s[g * 8 + g1], a1);
            }
            float mx0 = a0, mx1 = a1;
#pragma unroll
            for (int off = 1; off < 16; off <<= 1) {
                mx0 = fmaxf(mx0, __shfl_xor(mx0, off));
                mx1 = fmaxf(mx1, __shfl_xor(mx1, off));
            }
            const float e0 = __expf(a0 - mx0), e1 = __expf(a1 - mx1);
            float s0 = e0, s1 = e1;
#pragma unroll
            for (int off = 1; off < 16; off <<= 1) {
                s0 += __shfl_xor(s0, off);
                s1 += __shfl_xor(s1, off);
            }
            const float mf = idxs[(q << 4) + j] >= 0 ? 1.f : 0.f;
            wl[q * 128 + j * 8 + g0] = e0 * (1.f / s0) * mf;
            wl[q * 128 + j * 8 + g1] = e1 * (1.f / s1) * mf;
        }
    }
    __syncthreads();

    // ---- P6: out[q][c] = sum_j val[j][c] * w[j][c>>4]  (paired cols) ----
    {
        const int pc = t & 63;
        const int c0 = 2 * pc;
        const int g = pc >> 3;           // (2*pc)>>4
#pragma unroll
        for (int qq = 0; qq < 2; qq++) {
            const int q = 4 * qq + w;
            float s0 = 0.f, s1 = 0.f;
#pragma unroll
            for (int j = 0; j < KNN; j++) {
                const unsigned v = *(const unsigned*)(&fA[(q * 16 + j) * 136 + c0]);
                const float wv = wl[q * 128 + j * 8 + g];
                s0 = fmaf(bflo(v), wv, s0);
                s1 = fmaf(bfhi(v), wv, s1);
            }
            *(float2*)(&out[(size_t)(m0 + q) * C + c0]) = make_float2(s0, s1);
        }
    }
}

// ---------------------------------------------------------------------------
extern "C" void kernel_launch(void* const* d_in, const int* in_sizes, int n_in,
                              void* d_out, int out_size, void* d_ws, size_t ws_size,
                              hipStream_t stream)
{
    const float* query_feat    = (const float*)d_in[0];
    const float* context_feat  = (const float*)d_in[1];
    const float* query_coord   = (const float*)d_in[2];
    const float* context_coord = (const float*)d_in[3];
    const float* Wq    = (const float*)d_in[4];
    const float* bq    = (const float*)d_in[5];
    const float* gq    = (const float*)d_in[6];
    const float* betaq = (const float*)d_in[7];
    const float* Wk    = (const float*)d_in[8];
    const float* bk    = (const float*)d_in[9];
    const float* gk    = (const float*)d_in[10];
    const float* betak = (const float*)d_in[11];
    const float* Wv    = (const float*)d_in[12];
    const float* bv    = (const float*)d_in[13];
    const float* Wp1   = (const float*)d_in[14];
    const float* bp1   = (const float*)d_in[15];
    const float* gp1   = (const float*)d_in[16];
    const float* betap1= (const float*)d_in[17];
    const float* Wp2   = (const float*)d_in[18];
    const float* bp2   = (const float*)d_in[19];
    const float* Ww1   = (const float*)d_in[20];
    const float* bw1   = (const float*)d_in[21];
    const float* gw1   = (const float*)d_in[22];
    const float* betaw1= (const float*)d_in[23];
    const float* Ww2   = (const float*)d_in[24];
    const float* bw2   = (const float*)d_in[25];
    const int*   knn   = (const int*)d_in[26];

    const int M = in_sizes[0] / C;   // 16384
    const int N = in_sizes[1] / C;   // 131072

    // workspace: v (N*C bf16) | K' (N*G bf16) | Q' (M*G bf16) | prepped weights | cw1
    u16* vb = (u16*)d_ws;
    u16* Kp = vb + (size_t)N * C;
    u16* Qp = Kp + (size_t)N * G;
    u16* pw = Qp + (size_t)M * G;
    u16* pWk    = pw;
    u16* pWv    = pw + 16384;
    u16* pWq    = pw + 2 * 16384;
    u16* pWp2   = pw + 3 * 16384;
    u16* pWw1b  = pw + 4 * 16384;
    u16* pWp2pb = pw + 4 * 16384 + 4096;
    float* cw1  = (float*)(pw + 4 * 16384 + 2 * 4096);

    prep_w<<<18, 256, 0, stream>>>(Wk, Wv, Wq, Wp2, Ww1, bp2, pw, cw1);
    proj_all<<<N / 64 + M / 64, 256, 0, stream>>>(
        context_feat, query_feat,
        pWk, bk, gk, betak, pWv, bv,
        pWq, bq, gq, betaq, pWw1b,
        vb, Kp, Qp, N / 64);
    attn6<<<M / QB, 256, 0, stream>>>(vb, Kp, Qp, query_coord, context_coord,
                                      Wp1, bp1, gp1, betap1, pWp2, bp2,
                                      pWp2pb, cw1, bw1, gw1, betaw1, Ww2, bw2,
                                      knn, (float*)d_out);
}

// Round 9
// 206.364 us; speedup vs baseline: 1.0523x; 1.0155x over previous
//
#include <hip/hip_runtime.h>

#define C 128
#define G 8
#define KNN 16
#define QB 4
#define EPS 1e-5f

typedef unsigned short u16;
typedef __attribute__((ext_vector_type(8))) short short8;   // 8 bf16 = 4 VGPRs
typedef __attribute__((ext_vector_type(4))) float float4v;  // MFMA accumulator

union frag_u { short8 v; u16 u[8]; unsigned d[4]; };

__device__ inline u16 f2bf(float f) {
    unsigned u = __builtin_bit_cast(unsigned, f);
    unsigned r = (u + 0x7fffu + ((u >> 16) & 1u)) >> 16;
    return (u16)r;
}
__device__ inline float bf2f(u16 h) {
    unsigned u = ((unsigned)h) << 16;
    return __builtin_bit_cast(float, u);
}
// hardware packed f32->bf16 (RNE), 1 instr (guide T12 recipe, verified r3-r6)
__device__ inline unsigned pk2(float lo, float hi) {
    unsigned r;
    asm("v_cvt_pk_bf16_f32 %0, %1, %2" : "=v"(r) : "v"(lo), "v"(hi));
    return r;
}
__device__ inline u16 f2bf1(float f) { return (u16)pk2(f, f); }
__device__ inline float bflo(unsigned v) { return __builtin_bit_cast(float, v << 16); }
__device__ inline float bfhi(unsigned v) { return __builtin_bit_cast(float, v & 0xffff0000u); }

// ---------------------------------------------------------------------------
// Prep: swizzle weights into MFMA B-frag bf16 layout.  (verified r4-r6)
// ---------------------------------------------------------------------------
__global__ __launch_bounds__(256) void prep_w(
    const float* __restrict__ Wk, const float* __restrict__ Wv,
    const float* __restrict__ Wq, const float* __restrict__ Wp2,
    const float* __restrict__ Ww1, const float* __restrict__ bp2,
    u16* __restrict__ dst, float* __restrict__ cw1)
{
    __shared__ float w1s[C * G];
    const int b = blockIdx.x, t = threadIdx.x;
    if (b < 16) {
        const int mi = b >> 2, qt = b & 3;
        const float* W = mi == 0 ? Wk : mi == 1 ? Wv : mi == 2 ? Wq : Wp2;
        u16* d = dst + mi * 16384;
        for (int e = qt * 4096 + t; e < (qt + 1) * 4096; e += 256) {
            const int k = e >> 7, n = e & 127;
            const int cb = n >> 4, lan = n & 15;
            const int kk = k >> 5, quad = (k >> 3) & 3, j = k & 7;
            d[(((cb * 4 + kk) * 4 + quad) * 16 + lan) * 8 + j] = f2bf(W[e]);
        }
    } else if (b == 16) {
        u16* d = dst + 4 * 16384;
        for (int e = t; e < 4096; e += 256) {
            const int j = e & 7, lan = (e >> 3) & 15;
            const int quad = (e >> 7) & 3, kk = e >> 9;
            const int k = kk * 32 + quad * 8 + j;
            d[e] = lan < 8 ? f2bf(Ww1[k * G + lan]) : (u16)0;
        }
    } else {
        // Wp2' = Wp2 @ Ww1 -> B-frag; cw1 = bp2 @ Ww1   (Ww1 from LDS)
        u16* d = dst + 4 * 16384 + 4096;
        for (int e = t; e < 4096; e += 256) d[e] = 0;
        for (int e = t; e < C * G; e += 256) w1s[e] = Ww1[e];
        __syncthreads();
#pragma unroll
        for (int it = 0; it < 4; it++) {
            const int k = it * 32 + (t >> 3), g = t & 7;
            const float4* Wr = (const float4*)(Wp2 + k * C);
            float a = 0.f;
#pragma unroll 8
            for (int i4 = 0; i4 < 32; i4++) {
                const float4 wv = Wr[i4];
                a = fmaf(wv.x, w1s[(i4 * 4 + 0) * G + g], a);
                a = fmaf(wv.y, w1s[(i4 * 4 + 1) * G + g], a);
                a = fmaf(wv.z, w1s[(i4 * 4 + 2) * G + g], a);
                a = fmaf(wv.w, w1s[(i4 * 4 + 3) * G + g], a);
            }
            const int kk = k >> 5, quad = (k >> 3) & 3, j = k & 7;
            d[((kk * 4 + quad) * 16 + g) * 8 + j] = f2bf(a);
        }
        if (t < G) {
            float a = 0.f;
#pragma unroll 8
            for (int i = 0; i < C; i++) a = fmaf(bp2[i], w1s[i * G + t], a);
            cw1[t] = a;
        }
    }
}

// ---------------------------------------------------------------------------
// Fused projections.  (verified r4-r6)
// ---------------------------------------------------------------------------
__global__ __launch_bounds__(256) void proj_all(
    const float* __restrict__ Xc, const float* __restrict__ Xq,
    const u16* __restrict__ PWk, const float* __restrict__ bk,
    const float* __restrict__ gk, const float* __restrict__ betak,
    const u16* __restrict__ PWv, const float* __restrict__ bv,
    const u16* __restrict__ PWq, const float* __restrict__ bq,
    const float* __restrict__ gq, const float* __restrict__ betaq,
    const u16* __restrict__ PWw1b,
    u16* __restrict__ vout, u16* __restrict__ Kp, u16* __restrict__ Qp,
    int nkv)
{
    __shared__ u16 Xs[64 * 136];
    const int t = threadIdx.x;
    const int w = t >> 6, l = t & 63;
    const int quad = l >> 4, lan = l & 15;
    const bool isq = (int)blockIdx.x >= nkv;
    const long long row0 = (long long)(isq ? blockIdx.x - nkv : blockIdx.x) * 64;
    const float* X = isq ? Xq : Xc;

    // stage X tile -> bf16 LDS (hw cvt_pk)
    {
        const float4* Xv = (const float4*)(X + row0 * C);
#pragma unroll
        for (int i = 0; i < 8; i++) {
            const int e = t + 256 * i;
            const int r = e >> 5, c4 = e & 31;
            const float4 f = Xv[e];
            uint2 p;
            p.x = pk2(f.x, f.y);
            p.y = pk2(f.z, f.w);
            *(uint2*)(&Xs[r * 136 + c4 * 4]) = p;
        }
    }
    __syncthreads();

    if (!isq) {
        // ---- v pass (bias in acc init), packed bf16 in regs ----
        unsigned vp[2][4][2];
        {
            short8 Bf[2][4];
#pragma unroll
            for (int ct = 0; ct < 2; ct++) {
                const int cb = w * 2 + ct;
#pragma unroll
                for (int kk = 0; kk < 4; kk++)
                    Bf[ct][kk] = *(const short8*)(PWv + (((cb * 4 + kk) * 4 + quad) * 16 + lan) * 8);
            }
            const float b0v = bv[w * 32 + lan], b1v = bv[w * 32 + 16 + lan];
            float4v acc[2][4];
#pragma unroll
            for (int rt = 0; rt < 4; rt++) {
                acc[0][rt] = (float4v)b0v;
                acc[1][rt] = (float4v)b1v;
            }
#pragma unroll
            for (int rt = 0; rt < 4; rt++)
#pragma unroll
                for (int kk = 0; kk < 4; kk++) {
                    const short8 A = *(const short8*)(&Xs[(rt * 16 + lan) * 136 + kk * 32 + quad * 8]);
#pragma unroll
                    for (int ct = 0; ct < 2; ct++)
                        acc[ct][rt] = __builtin_amdgcn_mfma_f32_16x16x32_bf16(
                            A, Bf[ct][kk], acc[ct][rt], 0, 0, 0);
                }
#pragma unroll
            for (int ct = 0; ct < 2; ct++)
#pragma unroll
                for (int rt = 0; rt < 4; rt++)
#pragma unroll
                    for (int h = 0; h < 2; h++)
                        vp[ct][rt][h] = pk2(acc[ct][rt][2 * h], acc[ct][rt][2 * h + 1]);
        }
        // ---- k pass (bias in acc init), kept in regs ----
        float4v acck[2][4];
        {
            short8 Bf[2][4];
#pragma unroll
            for (int ct = 0; ct < 2; ct++) {
                const int cb = w * 2 + ct;
#pragma unroll
                for (int kk = 0; kk < 4; kk++)
                    Bf[ct][kk] = *(const short8*)(PWk + (((cb * 4 + kk) * 4 + quad) * 16 + lan) * 8);
            }
            const float b0k = bk[w * 32 + lan], b1k = bk[w * 32 + 16 + lan];
#pragma unroll
            for (int rt = 0; rt < 4; rt++) {
                acck[0][rt] = (float4v)b0k;
                acck[1][rt] = (float4v)b1k;
            }
#pragma unroll
            for (int rt = 0; rt < 4; rt++)
#pragma unroll
                for (int kk = 0; kk < 4; kk++) {
                    const short8 A = *(const short8*)(&Xs[(rt * 16 + lan) * 136 + kk * 32 + quad * 8]);
#pragma unroll
                    for (int ct = 0; ct < 2; ct++)
                        acck[ct][rt] = __builtin_amdgcn_mfma_f32_16x16x32_bf16(
                            A, Bf[ct][kk], acck[ct][rt], 0, 0, 0);
                }
        }
        __syncthreads();   // Xs A-reads done

        // k epilogue: y = fma(acc, sc, sh); relu -> Xs (row-major bf16)
#pragma unroll
        for (int ct = 0; ct < 2; ct++) {
            const int cg = w * 32 + ct * 16 + lan;
            const float sc = gk[cg] * rsqrtf(1.f + EPS);
            const float sh = betak[cg];
#pragma unroll
            for (int rt = 0; rt < 4; rt++)
#pragma unroll
                for (int reg = 0; reg < 4; reg++) {
                    float y = fmaf(acck[ct][rt][reg], sc, sh);
                    y = y > 0.f ? y : 0.f;
                    Xs[(rt * 16 + quad * 4 + reg) * 136 + cg] = f2bf1(y);
                }
        }
        __syncthreads();

        // K' = k @ Ww1 : wave w handles rows [16w,16w+16)
        {
            short8 Bw[4];
#pragma unroll
            for (int kk = 0; kk < 4; kk++)
                Bw[kk] = *(const short8*)(PWw1b + ((kk * 4 + quad) * 16 + lan) * 8);
            float4v ka = (float4v)0.f;
#pragma unroll
            for (int kk = 0; kk < 4; kk++) {
                const short8 A = *(const short8*)(&Xs[(w * 16 + lan) * 136 + kk * 32 + quad * 8]);
                ka = __builtin_amdgcn_mfma_f32_16x16x32_bf16(A, Bw[kk], ka, 0, 0, 0);
            }
            if (lan < G) {
#pragma unroll
                for (int reg = 0; reg < 4; reg++)
                    Kp[(row0 + w * 16 + quad * 4 + reg) * G + lan] = f2bf1(ka[reg]);
            }
        }
        __syncthreads();   // Xs K'-reads done

        // v epilogue (unpack) -> Xs -> coalesced store
#pragma unroll
        for (int ct = 0; ct < 2; ct++) {
            const int cg = w * 32 + ct * 16 + lan;
#pragma unroll
            for (int rt = 0; rt < 4; rt++)
#pragma unroll
                for (int h = 0; h < 2; h++) {
                    Xs[(rt * 16 + quad * 4 + 2 * h) * 136 + cg]     = (u16)(vp[ct][rt][h] & 0xffffu);
                    Xs[(rt * 16 + quad * 4 + 2 * h + 1) * 136 + cg] = (u16)(vp[ct][rt][h] >> 16);
                }
        }
        __syncthreads();
#pragma unroll
        for (int i = 0; i < 4; i++) {
            const int e = t + 256 * i;
            const int r = e >> 4, cc = (e & 15) * 8;
            *(short8*)(vout + (row0 + r) * C + cc) = *(const short8*)(&Xs[r * 136 + cc]);
        }
    } else {
        // ---- q path: bias in acc init; folded bn+relu; Q' = q@Ww1 ----
        float4v acc[2][4];
        {
            short8 Bf[2][4];
#pragma unroll
            for (int ct = 0; ct < 2; ct++) {
                const int cb = w * 2 + ct;
#pragma unroll
                for (int kk = 0; kk < 4; kk++)
                    Bf[ct][kk] = *(const short8*)(PWq + (((cb * 4 + kk) * 4 + quad) * 16 + lan) * 8);
            }
            const float b0q = bq[w * 32 + lan], b1q = bq[w * 32 + 16 + lan];
#pragma unroll
            for (int rt = 0; rt < 4; rt++) {
                acc[0][rt] = (float4v)b0q;
                acc[1][rt] = (float4v)b1q;
            }
#pragma unroll
            for (int rt = 0; rt < 4; rt++)
#pragma unroll
                for (int kk = 0; kk < 4; kk++) {
                    const short8 A = *(const short8*)(&Xs[(rt * 16 + lan) * 136 + kk * 32 + quad * 8]);
#pragma unroll
                    for (int ct = 0; ct < 2; ct++)
                        acc[ct][rt] = __builtin_amdgcn_mfma_f32_16x16x32_bf16(
                            A, Bf[ct][kk], acc[ct][rt], 0, 0, 0);
                }
        }
        __syncthreads();
#pragma unroll
        for (int ct = 0; ct < 2; ct++) {
            const int cg = w * 32 + ct * 16 + lan;
            const float sc = gq[cg] * rsqrtf(1.f + EPS);
            const float sh = betaq[cg];
#pragma unroll
            for (int rt = 0; rt < 4; rt++)
#pragma unroll
                for (int reg = 0; reg < 4; reg++) {
                    float y = fmaf(acc[ct][rt][reg], sc, sh);
                    y = y > 0.f ? y : 0.f;
                    Xs[(rt * 16 + quad * 4 + reg) * 136 + cg] = f2bf1(y);
                }
        }
        __syncthreads();
        {
            short8 Bw[4];
#pragma unroll
            for (int kk = 0; kk < 4; kk++)
                Bw[kk] = *(const short8*)(PWw1b + ((kk * 4 + quad) * 16 + lan) * 8);
            float4v qa = (float4v)0.f;
#pragma unroll
            for (int kk = 0; kk < 4; kk++) {
                const short8 A = *(const short8*)(&Xs[(w * 16 + lan) * 136 + kk * 32 + quad * 8]);
                qa = __builtin_amdgcn_mfma_f32_16x16x32_bf16(A, Bw[kk], qa, 0, 0, 0);
            }
            if (lan < G) {
#pragma unroll
                for (int reg = 0; reg < 4; reg++)
                    Qp[(row0 + w * 16 + quad * 4 + reg) * G + lan] = f2bf1(qa[reg]);
            }
        }
    }
}

// ---------------------------------------------------------------------------
// Attention v6.11 = verified r5-header attn (42.3 us) + ONLY the P1 retile
// (4 rows x 8 cols / thread, b128 LDS r/w; ps4 float4 staging verified r6).
// P2/P2b/P3/P5/P6 byte-identical to the verified kernel (wl [q][j][g],
// scalar wl reads/writes). Bisects the r7/r8 failure: pass => wl2/float4-read
// was the bug; fail => retile was the bug.
// ---------------------------------------------------------------------------
__global__ __launch_bounds__(256) void attn6(
    const u16* __restrict__ vbuf, const u16* __restrict__ Kp,
    const u16* __restrict__ Qp,
    const float* __restrict__ qcoord, const float* __restrict__ ccoord,
    const float* __restrict__ Wp1, const float* __restrict__ bp1,
    const float* __restrict__ gp1, const float* __restrict__ betap1,
    const u16* __restrict__ PWp2, const float* __restrict__ bp2,
    const u16* __restrict__ PWp2pb, const float* __restrict__ cw1,
    const float* __restrict__ bw1,
    const float* __restrict__ gw1, const float* __restrict__ betaw1,
    const float* __restrict__ Ww2, const float* __restrict__ bw2,
    const int* __restrict__ knn, float* __restrict__ out)
{
    __shared__ u16    fA[64 * 136];       // h1 -> peb -> val
    __shared__ u16    kgs[64 * G];        // gathered K' rows (bf16)
    __shared__ float  qps[QB * G];        // Q' rows (fp32)
    __shared__ float  pebp[64 * G];       // PEB' (fp32)
    __shared__ float  cw1s[G];
    __shared__ float  ww2s[G * G];        // Ww2 staged once
    __shared__ float4 ps4[64];            // packed pos (x,y,z,0)
    __shared__ int    idxs[64];
    __shared__ float  wl[QB * 16 * G];    // hw -> weights (in place), [q][j][g]

    const int t = threadIdx.x;
    const int w = t >> 6, l = t & 63;
    const int quad = l >> 4, lan = l & 15;
    const int m0 = blockIdx.x * QB;
    const int rsub = t >> 4;              // 0..15
    const int c8 = (t & 15) * 8;

    // ---- P0: v prefetch (regs), indices, positions, K'/Q'/cw1/Ww2 to LDS ----
    float mfr[4];
    frag_u vg[4];
#pragma unroll
    for (int p = 0; p < 4; p++) {
        const int ii = knn[m0 * KNN + p * 16 + rsub];
        mfr[p] = ii >= 0 ? 1.f : 0.f;
        const size_t i0 = ii >= 0 ? ii : 0;
        vg[p].v = *(const short8*)(vbuf + i0 * C + c8);
    }
    if (t < 64) {
        const int q = t >> 4;
        const int ii = knn[m0 * KNN + t];
        const float mf = ii >= 0 ? 1.f : 0.f;
        const int i0 = ii >= 0 ? ii : 0;
        idxs[t] = ii;
        float4 p4;
        p4.x = (ccoord[i0 * 3 + 0] - qcoord[(m0 + q) * 3 + 0]) * mf;
        p4.y = (ccoord[i0 * 3 + 1] - qcoord[(m0 + q) * 3 + 1]) * mf;
        p4.z = (ccoord[i0 * 3 + 2] - qcoord[(m0 + q) * 3 + 2]) * mf;
        p4.w = 0.f;
        ps4[t] = p4;
        *(short8*)(&kgs[t * G]) = *(const short8*)(Kp + (size_t)i0 * G);
    } else if (t < 64 + QB) {
        const int p = t - 64;
        frag_u qv;
        qv.v = *(const short8*)(Qp + (size_t)(m0 + p) * G);
#pragma unroll
        for (int j = 0; j < G; j++) qps[p * G + j] = bf2f(qv.u[j]);
    } else if (t < 68 + G) {
        cw1s[t - 68] = cw1[t - 68];
    } else if (t < 76 + G * G) {
        ww2s[t - 76] = Ww2[t - 76];
    }
    __syncthreads();

    // ---- P1: h1 = relu(bn(pos @ Wp1 + bp1)) -> fA (4 rows x 8 cols/thread) --
    {
        const float rsq = rsqrtf(1.f + EPS);
        const float4 gA = *(const float4*)(&gp1[c8]);
        const float4 gB = *(const float4*)(&gp1[c8 + 4]);
        const float4 bA = *(const float4*)(&bp1[c8]);
        const float4 bB = *(const float4*)(&bp1[c8 + 4]);
        const float4 eA = *(const float4*)(&betap1[c8]);
        const float4 eB = *(const float4*)(&betap1[c8 + 4]);
        const float4 xA = *(const float4*)(&Wp1[c8]);
        const float4 xB = *(const float4*)(&Wp1[c8 + 4]);
        const float4 yA = *(const float4*)(&Wp1[C + c8]);
        const float4 yB = *(const float4*)(&Wp1[C + c8 + 4]);
        const float4 zA = *(const float4*)(&Wp1[2 * C + c8]);
        const float4 zB = *(const float4*)(&Wp1[2 * C + c8 + 4]);
        const float gs[8] = {gA.x, gA.y, gA.z, gA.w, gB.x, gB.y, gB.z, gB.w};
        const float bs[8] = {bA.x, bA.y, bA.z, bA.w, bB.x, bB.y, bB.z, bB.w};
        const float es[8] = {eA.x, eA.y, eA.z, eA.w, eB.x, eB.y, eB.z, eB.w};
        const float xs[8] = {xA.x, xA.y, xA.z, xA.w, xB.x, xB.y, xB.z, xB.w};
        const float ys[8] = {yA.x, yA.y, yA.z, yA.w, yB.x, yB.y, yB.z, yB.w};
        const float zs[8] = {zA.x, zA.y, zA.z, zA.w, zB.x, zB.y, zB.z, zB.w};
        float w0f[8], w1f[8], w2f[8], bbf[8];
#pragma unroll
        for (int i2 = 0; i2 < 8; i2++) {
            const float sc = gs[i2] * rsq;
            w0f[i2] = xs[i2] * sc;
            w1f[i2] = ys[i2] * sc;
            w2f[i2] = zs[i2] * sc;
            bbf[i2] = fmaf(bs[i2], sc, es[i2]);
        }
#pragma unroll
        for (int rr = 0; rr < 4; rr++) {
            const int r = rsub * 4 + rr;
            const float4 p4 = ps4[r];
            frag_u o;
#pragma unroll
            for (int dd = 0; dd < 4; dd++) {
                const int ca = 2 * dd, cb2 = 2 * dd + 1;
                float ya = fmaf(p4.x, w0f[ca],
                           fmaf(p4.y, w1f[ca], fmaf(p4.z, w2f[ca], bbf[ca])));
                float yb = fmaf(p4.x, w0f[cb2],
                           fmaf(p4.y, w1f[cb2], fmaf(p4.z, w2f[cb2], bbf[cb2])));
                ya = ya > 0.f ? ya : 0.f;
                yb = yb > 0.f ? yb : 0.f;
                o.d[dd] = pk2(ya, yb);
            }
            *(short8*)(&fA[r * 136 + c8]) = o.v;
        }
    }
    __syncthreads();

    // ---- P2: peb = h1 @ Wp2 (+bp2 via acc init) + PEB' = h1 @ Wp2' ----
    float4v acc[2][4];
    float4v pp = (float4v)0.f;
    {
        short8 Bf[2][4];
#pragma unroll
        for (int ct = 0; ct < 2; ct++) {
            const int cb = w * 2 + ct;
#pragma unroll
            for (int kk = 0; kk < 4; kk++)
                Bf[ct][kk] = *(const short8*)(PWp2 + (((cb * 4 + kk) * 4 + quad) * 16 + lan) * 8);
        }
        const float b0 = bp2[w * 32 + lan], b1 = bp2[w * 32 + 16 + lan];
#pragma unroll
        for (int q = 0; q < 4; q++) {
            acc[0][q] = (float4v)b0;
            acc[1][q] = (float4v)b1;
        }
#pragma unroll
        for (int q = 0; q < 4; q++)
#pragma unroll
            for (int kk = 0; kk < 4; kk++) {
                const short8 A = *(const short8*)(&fA[(q * 16 + lan) * 136 + kk * 32 + quad * 8]);
#pragma unroll
                for (int ct = 0; ct < 2; ct++)
                    acc[ct][q] = __builtin_amdgcn_mfma_f32_16x16x32_bf16(
                        A, Bf[ct][kk], acc[ct][q], 0, 0, 0);
            }
        // PEB': wave w -> rows [16w,16w+16)
#pragma unroll
        for (int kk = 0; kk < 4; kk++) {
            const short8 Bp = *(const short8*)(PWp2pb + ((kk * 4 + quad) * 16 + lan) * 8);
            const short8 A = *(const short8*)(&fA[(w * 16 + lan) * 136 + kk * 32 + quad * 8]);
            pp = __builtin_amdgcn_mfma_f32_16x16x32_bf16(A, Bp, pp, 0, 0, 0);
        }
    }
    __syncthreads();   // all h1 reads done

    // ---- P2b: scatter peb (bf16, in place) and PEB' (fp32) ----
    {
#pragma unroll
        for (int ct = 0; ct < 2; ct++)
#pragma unroll
            for (int q = 0; q < 4; q++)
#pragma unroll
                for (int reg = 0; reg < 4; reg++)
                    fA[(q * 16 + quad * 4 + reg) * 136 + w * 32 + ct * 16 + lan] =
                        f2bf1(acc[ct][q][reg]);
        if (lan < G) {
#pragma unroll
            for (int reg = 0; reg < 4; reg++)
                pebp[(w * 16 + quad * 4 + reg) * G + lan] = pp[reg];
        }
    }
    __syncthreads();

    // ---- P3: val = vg*mf + peb -> fA (in place); logits -> wl (ALL lanes) ----
    {
#pragma unroll
        for (int p = 0; p < 4; p++) {
            const int r = p * 16 + rsub;
            const float mf = mfr[p];
            frag_u peb, o;
            peb.v = *(const short8*)(&fA[r * 136 + c8]);
#pragma unroll
            for (int dd = 0; dd < 4; dd++) {
                const unsigned pv = peb.d[dd], vv = vg[p].d[dd];
                o.d[dd] = pk2(fmaf(bflo(vv), mf, bflo(pv)),
                              fmaf(bfhi(vv), mf, bfhi(pv)));
            }
            *(short8*)(&fA[r * 136 + c8]) = o.v;   // exclusive slot
        }
    }
    {
        // lane -> (query w, neighbor j, groups g0=2*quad, g1=g0+1)
        const int j = l & 15;
        const int r = (w << 4) + j;
        const float mf = idxs[r] >= 0 ? 1.f : 0.f;
        const int g0 = 2 * quad, g1 = g0 + 1;
        const float L0 = bf2f(kgs[r * G + g0]) * mf - qps[w * G + g0]
                       + pebp[r * G + g0] + cw1s[g0] + bw1[g0];
        const float L1 = bf2f(kgs[r * G + g1]) * mf - qps[w * G + g1]
                       + pebp[r * G + g1] + cw1s[g1] + bw1[g1];
        const float y0 = L0 * (gw1[g0] * rsqrtf(1.f + EPS)) + betaw1[g0];
        const float y1 = L1 * (gw1[g1] * rsqrtf(1.f + EPS)) + betaw1[g1];
        wl[w * 128 + j * 8 + g0] = y0 > 0.f ? y0 : 0.f;
        wl[w * 128 + j * 8 + g1] = y1 > 0.f ? y1 : 0.f;
    }
    __syncthreads();

    // ---- P5: a = hw@Ww2 + bw2; softmax over j (16-lane butterfly); *mask ----
    {
        const int j = l & 15;
        const int g0 = 2 * quad, g1 = g0 + 1;
        float hw_[8];
#pragma unroll
        for (int g = 0; g < 8; g++) hw_[g] = wl[w * 128 + j * 8 + g];
        float a0 = bw2[g0], a1 = bw2[g1];
#pragma unroll
        for (int g = 0; g < 8; g++) {
            a0 = fmaf(hw_[g], ww2s[g * 8 + g0], a0);
            a1 = fmaf(hw_[g], ww2s[g * 8 + g1], a1);
        }
        float mx0 = a0, mx1 = a1;
#pragma unroll
        for (int off = 1; off < 16; off <<= 1) {
            mx0 = fmaxf(mx0, __shfl_xor(mx0, off));
            mx1 = fmaxf(mx1, __shfl_xor(mx1, off));
        }
        const float e0 = __expf(a0 - mx0), e1 = __expf(a1 - mx1);
        float s0 = e0, s1 = e1;
#pragma unroll
        for (int off = 1; off < 16; off <<= 1) {
            s0 += __shfl_xor(s0, off);
            s1 += __shfl_xor(s1, off);
        }
        const float mf = idxs[(w << 4) + j] >= 0 ? 1.f : 0.f;
        wl[w * 128 + j * 8 + g0] = e0 * (1.f / s0) * mf;
        wl[w * 128 + j * 8 + g1] = e1 * (1.f / s1) * mf;
    }
    __syncthreads();

    // ---- P6: out[q][c] = sum_j val[j][c] * w[j][c>>4]  (paired cols) ----
    {
        const int q = t >> 6;            // wave = query
        const int pc = t & 63;
        const int c0 = 2 * pc;
        const int g = pc >> 3;           // (2*pc)>>4
        float s0 = 0.f, s1 = 0.f;
#pragma unroll
        for (int j = 0; j < KNN; j++) {
            const unsigned v = *(const unsigned*)(&fA[(q * 16 + j) * 136 + c0]);
            const float wv = wl[q * 128 + j * 8 + g];
            s0 = fmaf(bflo(v), wv, s0);
            s1 = fmaf(bfhi(v), wv, s1);
        }
        *(float2*)(&out[(size_t)(m0 + q) * C + c0]) = make_float2(s0, s1);
    }
}

// ---------------------------------------------------------------------------
extern "C" void kernel_launch(void* const* d_in, const int* in_sizes, int n_in,
                              void* d_out, int out_size, void* d_ws, size_t ws_size,
                              hipStream_t stream)
{
    const float* query_feat    = (const float*)d_in[0];
    const float* context_feat  = (const float*)d_in[1];
    const float* query_coord   = (const float*)d_in[2];
    const float* context_coord = (const float*)d_in[3];
    const float* Wq    = (const float*)d_in[4];
    const float* bq    = (const float*)d_in[5];
    const float* gq    = (const float*)d_in[6];
    const float* betaq = (const float*)d_in[7];
    const float* Wk    = (const float*)d_in[8];
    const float* bk    = (const float*)d_in[9];
    const float* gk    = (const float*)d_in[10];
    const float* betak = (const float*)d_in[11];
    const float* Wv    = (const float*)d_in[12];
    const float* bv    = (const float*)d_in[13];
    const float* Wp1   = (const float*)d_in[14];
    const float* bp1   = (const float*)d_in[15];
    const float* gp1   = (const float*)d_in[16];
    const float* betap1= (const float*)d_in[17];
    const float* Wp2   = (const float*)d_in[18];
    const float* bp2   = (const float*)d_in[19];
    const float* Ww1   = (const float*)d_in[20];
    const float* bw1   = (const float*)d_in[21];
    const float* gw1   = (const float*)d_in[22];
    const float* betaw1= (const float*)d_in[23];
    const float* Ww2   = (const float*)d_in[24];
    const float* bw2   = (const float*)d_in[25];
    const int*   knn   = (const int*)d_in[26];

    const int M = in_sizes[0] / C;   // 16384
    const int N = in_sizes[1] / C;   // 131072

    // workspace: v (N*C bf16) | K' (N*G bf16) | Q' (M*G bf16) | prepped weights | cw1
    u16* vb = (u16*)d_ws;
    u16* Kp = vb + (size_t)N * C;
    u16* Qp = Kp + (size_t)N * G;
    u16* pw = Qp + (size_t)M * G;
    u16* pWk    = pw;
    u16* pWv    = pw + 16384;
    u16* pWq    = pw + 2 * 16384;
    u16* pWp2   = pw + 3 * 16384;
    u16* pWw1b  = pw + 4 * 16384;
    u16* pWp2pb = pw + 4 * 16384 + 4096;
    float* cw1  = (float*)(pw + 4 * 16384 + 2 * 4096);

    prep_w<<<18, 256, 0, stream>>>(Wk, Wv, Wq, Wp2, Ww1, bp2, pw, cw1);
    proj_all<<<N / 64 + M / 64, 256, 0, stream>>>(
        context_feat, query_feat,
        pWk, bk, gk, betak, pWv, bv,
        pWq, bq, gq, betaq, pWw1b,
        vb, Kp, Qp, N / 64);
    attn6<<<M / QB, 256, 0, stream>>>(vb, Kp, Qp, query_coord, context_coord,
                                      Wp1, bp1, gp1, betap1, pWp2, bp2,
                                      pWp2pb, cw1, bw1, gw1, betaw1, Ww2, bw2,
                                      knn, (float*)d_out);
}